// Round 1
// baseline (840.867 us; speedup 1.0000x reference)
//
#include <hip/hip_runtime.h>
#include <hip/hip_bf16.h>

typedef __attribute__((ext_vector_type(8))) __bf16 bf16x8;
typedef __attribute__((ext_vector_type(4))) float f32x4;

#define MFMA16(a, b, c) __builtin_amdgcn_mfma_f32_16x16x32_bf16((a), (b), (c), 0, 0, 0)

// ---------------- copy kernel (memory_bank -> d_out.mem[0:4]) ----------------
__global__ void copy_kernel(const float* __restrict__ in, float* __restrict__ out, int n4) {
    int i = blockIdx.x * blockDim.x + threadIdx.x;
    int stride = gridDim.x * blockDim.x;
    const float4* i4 = (const float4*)in;
    float4* o4 = (float4*)out;
    for (; i < n4; i += stride) o4[i] = i4[i];
}

// ---------------- LayerNorm (1024 cols, one block per row) ----------------
__global__ __launch_bounds__(256) void ln_kernel(const float* __restrict__ x,
                                                 const float* __restrict__ g,
                                                 const float* __restrict__ bta,
                                                 float* __restrict__ out) {
    int row = blockIdx.x;
    const float4 v = ((const float4*)(x + (size_t)row * 1024))[threadIdx.x];
    float s = v.x + v.y + v.z + v.w;
    float s2 = v.x * v.x + v.y * v.y + v.z * v.z + v.w * v.w;
#pragma unroll
    for (int off = 1; off < 64; off <<= 1) {
        s += __shfl_xor(s, off);
        s2 += __shfl_xor(s2, off);
    }
    __shared__ float rs[4], rs2[4];
    int wv = threadIdx.x >> 6;
    if ((threadIdx.x & 63) == 0) { rs[wv] = s; rs2[wv] = s2; }
    __syncthreads();
    s = rs[0] + rs[1] + rs[2] + rs[3];
    s2 = rs2[0] + rs2[1] + rs2[2] + rs2[3];
    float mean = s * (1.0f / 1024.0f);
    float var = s2 * (1.0f / 1024.0f) - mean * mean;
    float rstd = rsqrtf(var + 1e-5f);
    float4 gg = ((const float4*)g)[threadIdx.x];
    float4 bb = ((const float4*)bta)[threadIdx.x];
    float4 o;
    o.x = (v.x - mean) * rstd * gg.x + bb.x;
    o.y = (v.y - mean) * rstd * gg.y + bb.y;
    o.z = (v.z - mean) * rstd * gg.z + bb.z;
    o.w = (v.w - mean) * rstd * gg.w + bb.w;
    ((float4*)(out + (size_t)row * 1024))[threadIdx.x] = o;
}

// ---------------- bf16 MFMA GEMM, A,B f32 row-major; C = A[M,K] @ B[K,N] ----------------
// EPI 0: store bf16 (C*scale)
// EPI 1: store f32 (C + res[row,col])
// EPI 2: store f32 relu(C + bias[col])
// EPI 3: store f32 (C + bias[col] + res[row,col])
template <int EPI>
__global__ __launch_bounds__(256) void gemm_kernel(const float* __restrict__ A,
                                                   const float* __restrict__ B,
                                                   void* __restrict__ Cout,
                                                   const float* __restrict__ bias,
                                                   const float* __restrict__ res,
                                                   int M, int N, int K, float scale) {
    __shared__ __bf16 As[128][40];  // [row][k], pad to 40 (80B rows, 16B aligned)
    __shared__ __bf16 Bs[128][40];  // [col][k] (B^T layout)
    int bm = blockIdx.y * 128, bn = blockIdx.x * 128;
    int t = threadIdx.x;
    int lane = t & 63, wave = t >> 6;
    int wm = (wave >> 1) * 64, wn = (wave & 1) * 64;
    int l16 = lane & 15, l4 = lane >> 4;

    f32x4 acc[4][4];
#pragma unroll
    for (int m = 0; m < 4; m++)
#pragma unroll
        for (int n = 0; n < 4; n++) acc[m][n] = (f32x4){0.f, 0.f, 0.f, 0.f};

    int ar = t >> 1, ak = (t & 1) * 16;          // A staging: row, k-offset
    int bk = t >> 3, bc = (t & 7) * 16;          // B staging: k, col-offset

    for (int k0 = 0; k0 < K; k0 += 32) {
        // stage A tile [128][32] f32 -> bf16
        {
            const float* ap = A + (size_t)(bm + ar) * K + k0 + ak;
            float4 f0 = ((const float4*)ap)[0];
            float4 f1 = ((const float4*)ap)[1];
            float4 f2 = ((const float4*)ap)[2];
            float4 f3 = ((const float4*)ap)[3];
            float ta[16] = {f0.x, f0.y, f0.z, f0.w, f1.x, f1.y, f1.z, f1.w,
                            f2.x, f2.y, f2.z, f2.w, f3.x, f3.y, f3.z, f3.w};
            bf16x8 v0, v1;
#pragma unroll
            for (int j = 0; j < 8; j++) { v0[j] = (__bf16)ta[j]; v1[j] = (__bf16)ta[j + 8]; }
            *(bf16x8*)&As[ar][ak] = v0;
            *(bf16x8*)&As[ar][ak + 8] = v1;
        }
        // stage B tile [32][128] f32 -> bf16, transposed into Bs[col][k]
        {
            const float* bp = B + (size_t)(k0 + bk) * N + bn + bc;
            float4 f0 = ((const float4*)bp)[0];
            float4 f1 = ((const float4*)bp)[1];
            float4 f2 = ((const float4*)bp)[2];
            float4 f3 = ((const float4*)bp)[3];
            float tb[16] = {f0.x, f0.y, f0.z, f0.w, f1.x, f1.y, f1.z, f1.w,
                            f2.x, f2.y, f2.z, f2.w, f3.x, f3.y, f3.z, f3.w};
#pragma unroll
            for (int j = 0; j < 16; j++) Bs[bc + j][bk] = (__bf16)tb[j];
        }
        __syncthreads();

        bf16x8 af[4], bf[4];
#pragma unroll
        for (int m = 0; m < 4; m++) af[m] = *(const bf16x8*)&As[wm + m * 16 + l16][l4 * 8];
#pragma unroll
        for (int n = 0; n < 4; n++) bf[n] = *(const bf16x8*)&Bs[wn + n * 16 + l16][l4 * 8];
#pragma unroll
        for (int m = 0; m < 4; m++)
#pragma unroll
            for (int n = 0; n < 4; n++) acc[m][n] = MFMA16(af[m], bf[n], acc[m][n]);
        __syncthreads();
    }

    // epilogue: C layout col=lane&15, row=(lane>>4)*4+r
#pragma unroll
    for (int m = 0; m < 4; m++) {
#pragma unroll
        for (int r = 0; r < 4; r++) {
            int row = bm + wm + m * 16 + l4 * 4 + r;
#pragma unroll
            for (int n = 0; n < 4; n++) {
                int col = bn + wn + n * 16 + l16;
                float c = acc[m][n][r];
                size_t idx = (size_t)row * N + col;
                if (EPI == 0) {
                    ((__bf16*)Cout)[idx] = (__bf16)(c * scale);
                } else if (EPI == 1) {
                    ((float*)Cout)[idx] = c + res[idx];
                } else if (EPI == 2) {
                    ((float*)Cout)[idx] = fmaxf(c + bias[col], 0.0f);
                } else {
                    ((float*)Cout)[idx] = c + bias[col] + res[idx];
                }
            }
        }
    }
}

// ---------------- fused masked attention (flash-style, online softmax) ----------------
// grid = (32 = b*H, 16 q-blocks), block = 256 (4 waves x 16 queries)
#define LKV 5120
__global__ __launch_bounds__(256) void attn_kernel(const __bf16* __restrict__ Pq,
                                                   const __bf16* __restrict__ PK,
                                                   const __bf16* __restrict__ PV,
                                                   const unsigned char* __restrict__ mask,
                                                   float* __restrict__ ctx) {
    int bh = blockIdx.x;
    int b = bh >> 4, h = bh & 15;
    int wave = threadIdx.x >> 6, lane = threadIdx.x & 63;
    int l16 = lane & 15, l4 = lane >> 4;
    int q0 = blockIdx.y * 64 + wave * 16;

    __shared__ __bf16 Ks[32][72];       // [key][dh]
    __shared__ __bf16 Vt[64][40];       // [dh][key]
    __shared__ __bf16 Ps[4][16][40];    // per-wave P [q][key]

    // Q fragments (held in regs for whole loop); A-frag: row=l16, k-slice from l4
    bf16x8 qf[2];
    {
        const __bf16* pqrow = Pq + (size_t)(b * 1024 + q0 + l16) * 1024 + h * 64;
        qf[0] = *(const bf16x8*)(pqrow + l4 * 8);
        qf[1] = *(const bf16x8*)(pqrow + 32 + l4 * 8);
    }

    f32x4 acc[4];
#pragma unroll
    for (int n = 0; n < 4; n++) acc[n] = (f32x4){0.f, 0.f, 0.f, 0.f};
    float mrow[4] = {-1e30f, -1e30f, -1e30f, -1e30f};
    float lrow[4] = {0.f, 0.f, 0.f, 0.f};

    const unsigned char* mp = mask + (size_t)b * (1024u * 1024u);

    for (int kc = 0; kc < LKV; kc += 32) {
        // ---- stage K, V chunk (32 keys x 64 dh) ----
        {
            int key = threadIdx.x >> 3, d0 = (threadIdx.x & 7) * 8;
            int kg = kc + key;
            int lidx = kg >> 10, i = kg & 1023;
            size_t rowoff = (size_t)(lidx * 2048 + b * 1024 + i) * 1024 + h * 64 + d0;
            *(bf16x8*)(&Ks[key][d0]) = *(const bf16x8*)(PK + rowoff);
            bf16x8 vv = *(const bf16x8*)(PV + rowoff);
#pragma unroll
            for (int j = 0; j < 8; j++) Vt[d0 + j][key] = vv[j];
        }
        __syncthreads();

        // ---- S = Pq @ K^T  (two 16-key tiles) ----
        f32x4 s0 = (f32x4){0.f, 0.f, 0.f, 0.f};
        f32x4 s1 = (f32x4){0.f, 0.f, 0.f, 0.f};
        {
            bf16x8 k0a = *(const bf16x8*)(&Ks[l16][l4 * 8]);
            bf16x8 k0b = *(const bf16x8*)(&Ks[l16][32 + l4 * 8]);
            bf16x8 k1a = *(const bf16x8*)(&Ks[16 + l16][l4 * 8]);
            bf16x8 k1b = *(const bf16x8*)(&Ks[16 + l16][32 + l4 * 8]);
            s0 = MFMA16(qf[0], k0a, s0);
            s0 = MFMA16(qf[1], k0b, s0);
            s1 = MFMA16(qf[0], k1a, s1);
            s1 = MFMA16(qf[1], k1b, s1);
        }

        // ---- mask (True byte => -1e30, finite to avoid NaN on all-masked) ----
        int ki0 = (kc + l16) & 1023;
        int ki1 = (kc + 16 + l16) & 1023;
#pragma unroll
        for (int r = 0; r < 4; r++) {
            int q = q0 + l4 * 4 + r;
            if (mp[(size_t)q * 1024 + ki0]) s0[r] = -1e30f;
            if (mp[(size_t)q * 1024 + ki1]) s1[r] = -1e30f;
        }

        // ---- online softmax ----
        float pr0[4], pr1[4];
#pragma unroll
        for (int r = 0; r < 4; r++) {
            float vmax = fmaxf(s0[r], s1[r]);
#pragma unroll
            for (int off = 1; off < 16; off <<= 1) vmax = fmaxf(vmax, __shfl_xor(vmax, off));
            float mnew = fmaxf(mrow[r], vmax);
            if (mnew > mrow[r]) {
                float sc = __expf(mrow[r] - mnew);
                lrow[r] *= sc;
#pragma unroll
                for (int n = 0; n < 4; n++) acc[n][r] *= sc;
                mrow[r] = mnew;
            }
            float p0 = __expf(s0[r] - mrow[r]);
            float p1 = __expf(s1[r] - mrow[r]);
            float rsum = p0 + p1;
#pragma unroll
            for (int off = 1; off < 16; off <<= 1) rsum += __shfl_xor(rsum, off);
            lrow[r] += rsum;
            pr0[r] = p0;
            pr1[r] = p1;
        }

        // ---- P -> LDS (per-wave), then PV MFMA ----
#pragma unroll
        for (int r = 0; r < 4; r++) {
            Ps[wave][l4 * 4 + r][l16] = (__bf16)pr0[r];
            Ps[wave][l4 * 4 + r][16 + l16] = (__bf16)pr1[r];
        }
        __threadfence_block();  // lgkmcnt drain: cross-lane LDS visibility within wave
        {
            bf16x8 pf = *(const bf16x8*)(&Ps[wave][l16][l4 * 8]);
#pragma unroll
            for (int n = 0; n < 4; n++) {
                bf16x8 vf = *(const bf16x8*)(&Vt[n * 16 + l16][l4 * 8]);
                acc[n] = MFMA16(pf, vf, acc[n]);
            }
        }
        __syncthreads();
    }

    // ---- finalize: ctx = acc / l ----
#pragma unroll
    for (int r = 0; r < 4; r++) {
        float inv = 1.0f / lrow[r];
        int q = q0 + l4 * 4 + r;
        float* crow = ctx + (size_t)(b * 1024 + q) * 1024 + h * 64;
#pragma unroll
        for (int n = 0; n < 4; n++) crow[n * 16 + l16] = acc[n][r] * inv;
    }
}

// ---------------- launcher ----------------
extern "C" void kernel_launch(void* const* d_in, const int* in_sizes, int n_in,
                              void* d_out, int out_size, void* d_ws, size_t ws_size,
                              hipStream_t stream) {
    const float* x = (const float*)d_in[0];
    const float* memory_bank = (const float*)d_in[1];
    const unsigned char* attn_mask = (const unsigned char*)d_in[2];  // numpy bool bytes
    const float* ln1_g = (const float*)d_in[3];
    const float* ln1_b = (const float*)d_in[4];
    const float* Wq = (const float*)d_in[5];
    const float* Wk = (const float*)d_in[6];
    const float* Wv = (const float*)d_in[7];
    const float* Wo = (const float*)d_in[8];
    const float* ln2_g = (const float*)d_in[9];
    const float* ln2_b = (const float*)d_in[10];
    const float* W1 = (const float*)d_in[11];
    const float* b1 = (const float*)d_in[12];
    const float* W2 = (const float*)d_in[13];
    const float* b2 = (const float*)d_in[14];

    float* out = (float*)d_out;                 // [2,1024,1024]
    float* mem_out = out + 2097152;             // [5,2,1024,1024]
    float* q_out = mem_out + 4 * 2097152;       // mem[4] = LN1(x)

    char* ws = (char*)d_ws;
    __bf16* Pq = (__bf16*)ws;                       // [0, 4MB)
    __bf16* PK = (__bf16*)(ws + (4u << 20));        // [4, 24MB)
    __bf16* PV = (__bf16*)(ws + (24u << 20));       // [24, 44MB)
    float* ctx = (float*)(ws + (44u << 20));        // [44, 52MB)
    float* x2 = (float*)ws;                         // alias [0, 8MB)  (Pq/PK dead)
    float* fln = (float*)(ws + (8u << 20));         // [8, 16MB)
    float* h1 = (float*)(ws + (16u << 20));         // [16, 48MB) (PK/PV/ctx dead)

    // 1. mem concat: copy bank + LN1(x) as layer 4
    copy_kernel<<<2048, 256, 0, stream>>>(memory_bank, mem_out, 2097152);
    ln_kernel<<<2048, 256, 0, stream>>>(x, ln1_g, ln1_b, q_out);

    // 2. projections (bf16 outputs)
    gemm_kernel<0><<<dim3(8, 16), 256, 0, stream>>>(q_out, Wq, Pq, nullptr, nullptr,
                                                    2048, 1024, 1024, 0.125f);
    gemm_kernel<0><<<dim3(8, 80), 256, 0, stream>>>(mem_out, Wk, PK, nullptr, nullptr,
                                                    10240, 1024, 1024, 1.0f);
    gemm_kernel<0><<<dim3(8, 80), 256, 0, stream>>>(mem_out, Wv, PV, nullptr, nullptr,
                                                    10240, 1024, 1024, 1.0f);

    // 3. attention
    attn_kernel<<<dim3(32, 16), 256, 0, stream>>>(Pq, PK, PV, attn_mask, ctx);

    // 4. Wo + residual -> x2
    gemm_kernel<1><<<dim3(8, 16), 256, 0, stream>>>(ctx, Wo, x2, nullptr, x,
                                                    2048, 1024, 1024, 1.0f);
    // 5. FFN
    ln_kernel<<<2048, 256, 0, stream>>>(x2, ln2_g, ln2_b, fln);
    gemm_kernel<2><<<dim3(32, 16), 256, 0, stream>>>(fln, W1, h1, b1, nullptr,
                                                     2048, 4096, 1024, 1.0f);
    gemm_kernel<3><<<dim3(8, 16), 256, 0, stream>>>(h1, W2, out, b2, x2,
                                                    2048, 1024, 4096, 1.0f);
}

// Round 2
// 694.233 us; speedup vs baseline: 1.2112x; 1.2112x over previous
//
#include <hip/hip_runtime.h>
#include <hip/hip_bf16.h>

typedef __attribute__((ext_vector_type(8))) __bf16 bf16x8;
typedef __attribute__((ext_vector_type(4))) float f32x4;

#define MFMA16(a, b, c) __builtin_amdgcn_mfma_f32_16x16x32_bf16((a), (b), (c), 0, 0, 0)

// ---------------- copy kernel (memory_bank -> d_out.mem[0:4]) ----------------
__global__ void copy_kernel(const float* __restrict__ in, float* __restrict__ out, int n4) {
    int i = blockIdx.x * blockDim.x + threadIdx.x;
    int stride = gridDim.x * blockDim.x;
    const float4* i4 = (const float4*)in;
    float4* o4 = (float4*)out;
    for (; i < n4; i += stride) o4[i] = i4[i];
}

// ---------------- LayerNorm (1024 cols, one block per row) ----------------
__global__ __launch_bounds__(256) void ln_kernel(const float* __restrict__ x,
                                                 const float* __restrict__ g,
                                                 const float* __restrict__ bta,
                                                 float* __restrict__ out) {
    int row = blockIdx.x;
    const float4 v = ((const float4*)(x + (size_t)row * 1024))[threadIdx.x];
    float s = v.x + v.y + v.z + v.w;
    float s2 = v.x * v.x + v.y * v.y + v.z * v.z + v.w * v.w;
#pragma unroll
    for (int off = 1; off < 64; off <<= 1) {
        s += __shfl_xor(s, off);
        s2 += __shfl_xor(s2, off);
    }
    __shared__ float rs[4], rs2[4];
    int wv = threadIdx.x >> 6;
    if ((threadIdx.x & 63) == 0) { rs[wv] = s; rs2[wv] = s2; }
    __syncthreads();
    s = rs[0] + rs[1] + rs[2] + rs[3];
    s2 = rs2[0] + rs2[1] + rs2[2] + rs2[3];
    float mean = s * (1.0f / 1024.0f);
    float var = s2 * (1.0f / 1024.0f) - mean * mean;
    float rstd = rsqrtf(var + 1e-5f);
    float4 gg = ((const float4*)g)[threadIdx.x];
    float4 bb = ((const float4*)bta)[threadIdx.x];
    float4 o;
    o.x = (v.x - mean) * rstd * gg.x + bb.x;
    o.y = (v.y - mean) * rstd * gg.y + bb.y;
    o.z = (v.z - mean) * rstd * gg.z + bb.z;
    o.w = (v.w - mean) * rstd * gg.w + bb.w;
    ((float4*)(out + (size_t)row * 1024))[threadIdx.x] = o;
}

// ---------------- bf16 MFMA GEMM, A,B f32 row-major; C = A[M,K] @ B[K,N] ----------------
template <int EPI>
__global__ __launch_bounds__(256) void gemm_kernel(const float* __restrict__ A,
                                                   const float* __restrict__ B,
                                                   void* __restrict__ Cout,
                                                   const float* __restrict__ bias,
                                                   const float* __restrict__ res,
                                                   int M, int N, int K, float scale) {
    __shared__ __bf16 As[128][40];
    __shared__ __bf16 Bs[128][40];
    int bm = blockIdx.y * 128, bn = blockIdx.x * 128;
    int t = threadIdx.x;
    int lane = t & 63, wave = t >> 6;
    int wm = (wave >> 1) * 64, wn = (wave & 1) * 64;
    int l16 = lane & 15, l4 = lane >> 4;

    f32x4 acc[4][4];
#pragma unroll
    for (int m = 0; m < 4; m++)
#pragma unroll
        for (int n = 0; n < 4; n++) acc[m][n] = (f32x4){0.f, 0.f, 0.f, 0.f};

    int ar = t >> 1, ak = (t & 1) * 16;
    int bk = t >> 3, bc = (t & 7) * 16;

    for (int k0 = 0; k0 < K; k0 += 32) {
        {
            const float* ap = A + (size_t)(bm + ar) * K + k0 + ak;
            float4 f0 = ((const float4*)ap)[0];
            float4 f1 = ((const float4*)ap)[1];
            float4 f2 = ((const float4*)ap)[2];
            float4 f3 = ((const float4*)ap)[3];
            float ta[16] = {f0.x, f0.y, f0.z, f0.w, f1.x, f1.y, f1.z, f1.w,
                            f2.x, f2.y, f2.z, f2.w, f3.x, f3.y, f3.z, f3.w};
            bf16x8 v0, v1;
#pragma unroll
            for (int j = 0; j < 8; j++) { v0[j] = (__bf16)ta[j]; v1[j] = (__bf16)ta[j + 8]; }
            *(bf16x8*)&As[ar][ak] = v0;
            *(bf16x8*)&As[ar][ak + 8] = v1;
        }
        {
            const float* bp = B + (size_t)(k0 + bk) * N + bn + bc;
            float4 f0 = ((const float4*)bp)[0];
            float4 f1 = ((const float4*)bp)[1];
            float4 f2 = ((const float4*)bp)[2];
            float4 f3 = ((const float4*)bp)[3];
            float tb[16] = {f0.x, f0.y, f0.z, f0.w, f1.x, f1.y, f1.z, f1.w,
                            f2.x, f2.y, f2.z, f2.w, f3.x, f3.y, f3.z, f3.w};
#pragma unroll
            for (int j = 0; j < 16; j++) Bs[bc + j][bk] = (__bf16)tb[j];
        }
        __syncthreads();

        bf16x8 af[4], bfr[4];
#pragma unroll
        for (int m = 0; m < 4; m++) af[m] = *(const bf16x8*)&As[wm + m * 16 + l16][l4 * 8];
#pragma unroll
        for (int n = 0; n < 4; n++) bfr[n] = *(const bf16x8*)&Bs[wn + n * 16 + l16][l4 * 8];
#pragma unroll
        for (int m = 0; m < 4; m++)
#pragma unroll
            for (int n = 0; n < 4; n++) acc[m][n] = MFMA16(af[m], bfr[n], acc[m][n]);
        __syncthreads();
    }

#pragma unroll
    for (int m = 0; m < 4; m++) {
#pragma unroll
        for (int r = 0; r < 4; r++) {
            int row = bm + wm + m * 16 + l4 * 4 + r;
#pragma unroll
            for (int n = 0; n < 4; n++) {
                int col = bn + wn + n * 16 + l16;
                float c = acc[m][n][r];
                size_t idx = (size_t)row * N + col;
                if (EPI == 0) {
                    ((__bf16*)Cout)[idx] = (__bf16)(c * scale);
                } else if (EPI == 1) {
                    ((float*)Cout)[idx] = c + res[idx];
                } else if (EPI == 2) {
                    ((float*)Cout)[idx] = fmaxf(c + bias[col], 0.0f);
                } else {
                    ((float*)Cout)[idx] = c + bias[col] + res[idx];
                }
            }
        }
    }
}

// ---------------- fused masked attention (flash-style, online softmax) ----------------
// grid = (32 = b*H, 16 q-blocks), block = 512 (2 key-groups x 4 waves x 16 queries)
// group g handles keys [g*2560, (g+1)*2560) in 40 chunks of 64; in-LDS merge at end.
#define LKV 5120
#define KHALF 2560
#define CK 64
#define NCH 40
__global__ __launch_bounds__(512, 4) void attn_kernel(const __bf16* __restrict__ Pq,
                                                      const __bf16* __restrict__ PK,
                                                      const __bf16* __restrict__ PV,
                                                      const unsigned char* __restrict__ mask,
                                                      float* __restrict__ ctx) {
    int bh = blockIdx.x;
    int b = bh >> 4, h = bh & 15;
    int wave = threadIdx.x >> 6, lane = threadIdx.x & 63;
    int grp = wave >> 2, wv = wave & 3;
    int l16 = lane & 15, l4 = lane >> 4;
    int q0 = blockIdx.y * 64 + wv * 16;

    __shared__ __bf16 Ks[2][64][72];   // [grp][key][dh]
    __shared__ __bf16 Vt[2][64][72];   // [grp][dh][key ^ ((dh>>3)<<3)]  (swizzled)
    __shared__ __bf16 Ps[8][16][72];   // per-wave P [q][key]

    // Q fragments (row q = l16, k-slice from l4)
    bf16x8 qf[2];
    {
        const __bf16* pqrow = Pq + (size_t)(b * 1024 + q0 + l16) * 1024 + h * 64;
        qf[0] = *(const bf16x8*)(pqrow + l4 * 8);
        qf[1] = *(const bf16x8*)(pqrow + 32 + l4 * 8);
    }

    f32x4 acc[4];
#pragma unroll
    for (int n = 0; n < 4; n++) acc[n] = (f32x4){0.f, 0.f, 0.f, 0.f};
    float mrow[4] = {-1e30f, -1e30f, -1e30f, -1e30f};
    float lrow[4] = {0.f, 0.f, 0.f, 0.f};

    const unsigned char* mp = mask + (size_t)b * (1024u * 1024u);

    // staging assignment (per 256-thread group)
    int tl = threadIdx.x & 255;
    int skey = tl >> 2;              // 0..63
    int sd0 = (tl & 3) << 4;         // 0,16,32,48
    int kgbase = grp * KHALF;

    bf16x8 rk0, rk1, rv0, rv1;
    {
        int kg = kgbase + skey;
        int lidx = kg >> 10, i = kg & 1023;
        size_t off = ((size_t)(lidx * 2048 + b * 1024 + i) << 10) + h * 64 + sd0;
        rk0 = *(const bf16x8*)(PK + off);
        rk1 = *(const bf16x8*)(PK + off + 8);
        rv0 = *(const bf16x8*)(PV + off);
        rv1 = *(const bf16x8*)(PV + off + 8);
    }

    for (int t = 0; t < NCH; t++) {
        // ---- write staged regs -> LDS ----
        *(bf16x8*)&Ks[grp][skey][sd0] = rk0;
        *(bf16x8*)&Ks[grp][skey][sd0 + 8] = rk1;
#pragma unroll
        for (int j = 0; j < 8; j++) {
            int row = sd0 + j;
            Vt[grp][row][skey ^ ((row >> 3) << 3)] = rv0[j];
            int row2 = sd0 + 8 + j;
            Vt[grp][row2][skey ^ ((row2 >> 3) << 3)] = rv1[j];
        }
        __syncthreads();

        // ---- prefetch next chunk (completes under compute) ----
        if (t + 1 < NCH) {
            int kg = kgbase + (t + 1) * CK + skey;
            int lidx = kg >> 10, i = kg & 1023;
            size_t off = ((size_t)(lidx * 2048 + b * 1024 + i) << 10) + h * 64 + sd0;
            rk0 = *(const bf16x8*)(PK + off);
            rk1 = *(const bf16x8*)(PK + off + 8);
            rv0 = *(const bf16x8*)(PV + off);
            rv1 = *(const bf16x8*)(PV + off + 8);
        }

        // ---- S = Pq @ K^T  (four 16-key tiles) ----
        f32x4 s[4];
#pragma unroll
        for (int tile = 0; tile < 4; tile++) {
            s[tile] = (f32x4){0.f, 0.f, 0.f, 0.f};
            bf16x8 ka = *(const bf16x8*)&Ks[grp][tile * 16 + l16][l4 * 8];
            bf16x8 kb = *(const bf16x8*)&Ks[grp][tile * 16 + l16][32 + l4 * 8];
            s[tile] = MFMA16(qf[0], ka, s[tile]);
            s[tile] = MFMA16(qf[1], kb, s[tile]);
        }

        // ---- mask + online softmax + P store ----
        int kloc = (kgbase + t * CK) & 1023;
#pragma unroll
        for (int r = 0; r < 4; r++) {
            const unsigned char* mq = mp + (size_t)(q0 + l4 * 4 + r) * 1024 + kloc + l16;
            float s0r = s[0][r]; if (mq[0])  s0r = -1e30f;
            float s1r = s[1][r]; if (mq[16]) s1r = -1e30f;
            float s2r = s[2][r]; if (mq[32]) s2r = -1e30f;
            float s3r = s[3][r]; if (mq[48]) s3r = -1e30f;
            float vmax = fmaxf(fmaxf(s0r, s1r), fmaxf(s2r, s3r));
#pragma unroll
            for (int off = 1; off < 16; off <<= 1) vmax = fmaxf(vmax, __shfl_xor(vmax, off));
            float mnew = fmaxf(mrow[r], vmax);
            if (mnew > mrow[r]) {
                float sc = __expf(mrow[r] - mnew);
                lrow[r] *= sc;
#pragma unroll
                for (int n = 0; n < 4; n++) acc[n][r] *= sc;
                mrow[r] = mnew;
            }
            float p0 = __expf(s0r - mnew);
            float p1 = __expf(s1r - mnew);
            float p2 = __expf(s2r - mnew);
            float p3 = __expf(s3r - mnew);
            float rsum = (p0 + p1) + (p2 + p3);
#pragma unroll
            for (int off = 1; off < 16; off <<= 1) rsum += __shfl_xor(rsum, off);
            lrow[r] += rsum;
            Ps[wave][l4 * 4 + r][l16] = (__bf16)p0;
            Ps[wave][l4 * 4 + r][16 + l16] = (__bf16)p1;
            Ps[wave][l4 * 4 + r][32 + l16] = (__bf16)p2;
            Ps[wave][l4 * 4 + r][48 + l16] = (__bf16)p3;
        }

        // ---- PV ----
#pragma unroll
        for (int kk = 0; kk < 2; kk++) {
            bf16x8 pf = *(const bf16x8*)&Ps[wave][l16][kk * 32 + l4 * 8];
#pragma unroll
            for (int n = 0; n < 4; n++) {
                int row = n * 16 + l16;
                int colblk = (kk * 32 + l4 * 8) ^ ((row >> 3) << 3);
                bf16x8 vf = *(const bf16x8*)&Vt[grp][row][colblk];
                acc[n] = MFMA16(pf, vf, acc[n]);
            }
        }
        __syncthreads();
    }

    // ---- in-block merge of the two key-groups ----
    float* exAcc = (float*)&Ks[0][0][0];   // 4 waves x 16 q x 64 dh f32 = 16KB (fits in Ks)
    float* exM = (float*)&Vt[0][0][0];     // 64 floats
    float* exL = exM + 64;
    if (grp == 1) {
#pragma unroll
        for (int n = 0; n < 4; n++)
#pragma unroll
            for (int r = 0; r < 4; r++)
                exAcc[(wv * 16 + l4 * 4 + r) * 64 + n * 16 + l16] = acc[n][r];
        if (l16 == 0) {
#pragma unroll
            for (int r = 0; r < 4; r++) {
                exM[wv * 16 + l4 * 4 + r] = mrow[r];
                exL[wv * 16 + l4 * 4 + r] = lrow[r];
            }
        }
    }
    __syncthreads();
    if (grp == 0) {
#pragma unroll
        for (int r = 0; r < 4; r++) {
            int qi = l4 * 4 + r;
            float m1 = exM[wv * 16 + qi], l1 = exL[wv * 16 + qi];
            float M = fmaxf(mrow[r], m1);
            float e0 = __expf(mrow[r] - M), e1 = __expf(m1 - M);
            float inv = 1.0f / (lrow[r] * e0 + l1 * e1);
            int q = q0 + qi;
            float* crow = ctx + ((size_t)(b * 1024 + q) << 10) + h * 64;
#pragma unroll
            for (int n = 0; n < 4; n++)
                crow[n * 16 + l16] = (acc[n][r] * e0 + exAcc[(wv * 16 + qi) * 64 + n * 16 + l16] * e1) * inv;
        }
    }
}

// ---------------- launcher ----------------
extern "C" void kernel_launch(void* const* d_in, const int* in_sizes, int n_in,
                              void* d_out, int out_size, void* d_ws, size_t ws_size,
                              hipStream_t stream) {
    const float* x = (const float*)d_in[0];
    const float* memory_bank = (const float*)d_in[1];
    const unsigned char* attn_mask = (const unsigned char*)d_in[2];
    const float* ln1_g = (const float*)d_in[3];
    const float* ln1_b = (const float*)d_in[4];
    const float* Wq = (const float*)d_in[5];
    const float* Wk = (const float*)d_in[6];
    const float* Wv = (const float*)d_in[7];
    const float* Wo = (const float*)d_in[8];
    const float* ln2_g = (const float*)d_in[9];
    const float* ln2_b = (const float*)d_in[10];
    const float* W1 = (const float*)d_in[11];
    const float* b1 = (const float*)d_in[12];
    const float* W2 = (const float*)d_in[13];
    const float* b2 = (const float*)d_in[14];

    float* out = (float*)d_out;                 // [2,1024,1024]
    float* mem_out = out + 2097152;             // [5,2,1024,1024]
    float* q_out = mem_out + 4 * 2097152;       // mem[4] = LN1(x)

    char* ws = (char*)d_ws;
    __bf16* Pq = (__bf16*)ws;                       // [0, 4MB)
    __bf16* PK = (__bf16*)(ws + (4u << 20));        // [4, 24MB)
    __bf16* PV = (__bf16*)(ws + (24u << 20));       // [24, 44MB)
    float* ctx = (float*)(ws + (44u << 20));        // [44, 52MB)
    float* x2 = (float*)ws;                         // alias [0, 8MB)  (Pq/PK dead)
    float* fln = (float*)(ws + (8u << 20));         // [8, 16MB)
    float* h1 = (float*)(ws + (16u << 20));         // [16, 48MB) (PK/PV/ctx dead)

    // 1. mem concat: copy bank + LN1(x) as layer 4
    copy_kernel<<<2048, 256, 0, stream>>>(memory_bank, mem_out, 2097152);
    ln_kernel<<<2048, 256, 0, stream>>>(x, ln1_g, ln1_b, q_out);

    // 2. projections (bf16 outputs)
    gemm_kernel<0><<<dim3(8, 16), 256, 0, stream>>>(q_out, Wq, Pq, nullptr, nullptr,
                                                    2048, 1024, 1024, 0.125f);
    gemm_kernel<0><<<dim3(8, 80), 256, 0, stream>>>(mem_out, Wk, PK, nullptr, nullptr,
                                                    10240, 1024, 1024, 1.0f);
    gemm_kernel<0><<<dim3(8, 80), 256, 0, stream>>>(mem_out, Wv, PV, nullptr, nullptr,
                                                    10240, 1024, 1024, 1.0f);

    // 3. attention
    attn_kernel<<<dim3(32, 16), 512, 0, stream>>>(Pq, PK, PV, attn_mask, ctx);

    // 4. Wo + residual -> x2
    gemm_kernel<1><<<dim3(8, 16), 256, 0, stream>>>(ctx, Wo, x2, nullptr, x,
                                                    2048, 1024, 1024, 1.0f);
    // 5. FFN
    ln_kernel<<<2048, 256, 0, stream>>>(x2, ln2_g, ln2_b, fln);
    gemm_kernel<2><<<dim3(32, 16), 256, 0, stream>>>(fln, W1, h1, b1, nullptr,
                                                     2048, 4096, 1024, 1.0f);
    gemm_kernel<3><<<dim3(8, 16), 256, 0, stream>>>(h1, W2, out, b2, x2,
                                                    2048, 1024, 4096, 1.0f);
}

// Round 3
// 481.623 us; speedup vs baseline: 1.7459x; 1.4414x over previous
//
#include <hip/hip_runtime.h>
#include <hip/hip_bf16.h>

typedef __attribute__((ext_vector_type(8))) __bf16 bf16x8;
typedef __attribute__((ext_vector_type(4))) __bf16 bf16x4;
typedef __attribute__((ext_vector_type(4))) float f32x4;

#define MFMA16(a, b, c) __builtin_amdgcn_mfma_f32_16x16x32_bf16((a), (b), (c), 0, 0, 0)

__device__ __forceinline__ void gll16(const void* g, void* l) {
    __builtin_amdgcn_global_load_lds((const __attribute__((address_space(1))) void*)g,
                                     (__attribute__((address_space(3))) void*)l,
                                     16, 0, 0);
}

// ---------------- copy kernel (memory_bank -> d_out.mem[0:4]) ----------------
__global__ void copy_kernel(const float* __restrict__ in, float* __restrict__ out, int n4) {
    int i = blockIdx.x * blockDim.x + threadIdx.x;
    int stride = gridDim.x * blockDim.x;
    const float4* i4 = (const float4*)in;
    float4* o4 = (float4*)out;
    for (; i < n4; i += stride) o4[i] = i4[i];
}

// ---------------- LayerNorm (1024 cols, one block per row); f32 and/or bf16 out ----------------
__global__ __launch_bounds__(256) void ln_kernel(const float* __restrict__ x,
                                                 const float* __restrict__ g,
                                                 const float* __restrict__ bta,
                                                 float* __restrict__ outf,
                                                 __bf16* __restrict__ outb) {
    int row = blockIdx.x;
    const float4 v = ((const float4*)(x + (size_t)row * 1024))[threadIdx.x];
    float s = v.x + v.y + v.z + v.w;
    float s2 = v.x * v.x + v.y * v.y + v.z * v.z + v.w * v.w;
#pragma unroll
    for (int off = 1; off < 64; off <<= 1) {
        s += __shfl_xor(s, off);
        s2 += __shfl_xor(s2, off);
    }
    __shared__ float rs[4], rs2[4];
    int wv = threadIdx.x >> 6;
    if ((threadIdx.x & 63) == 0) { rs[wv] = s; rs2[wv] = s2; }
    __syncthreads();
    s = rs[0] + rs[1] + rs[2] + rs[3];
    s2 = rs2[0] + rs2[1] + rs2[2] + rs2[3];
    float mean = s * (1.0f / 1024.0f);
    float var = s2 * (1.0f / 1024.0f) - mean * mean;
    float rstd = rsqrtf(var + 1e-5f);
    float4 gg = ((const float4*)g)[threadIdx.x];
    float4 bb = ((const float4*)bta)[threadIdx.x];
    float4 o;
    o.x = (v.x - mean) * rstd * gg.x + bb.x;
    o.y = (v.y - mean) * rstd * gg.y + bb.y;
    o.z = (v.z - mean) * rstd * gg.z + bb.z;
    o.w = (v.w - mean) * rstd * gg.w + bb.w;
    if (outf) ((float4*)(outf + (size_t)row * 1024))[threadIdx.x] = o;
    if (outb) {
        bf16x4 ob = {(__bf16)o.x, (__bf16)o.y, (__bf16)o.z, (__bf16)o.w};
        ((bf16x4*)(outb + (size_t)row * 1024))[threadIdx.x] = ob;
    }
}

// ---------------- transpose+convert: in f32 [K][N] -> out bf16 [N][K] ----------------
__global__ __launch_bounds__(256) void transpose_conv_kernel(const float* __restrict__ in,
                                                             __bf16* __restrict__ out,
                                                             int K, int N) {
    __shared__ float tile[32][33];
    int n0 = blockIdx.x * 32, k0 = blockIdx.y * 32;
    int tx = threadIdx.x & 31, ty = threadIdx.x >> 5;  // ty 0..7
#pragma unroll
    for (int i = 0; i < 4; i++)
        tile[ty + i * 8][tx] = in[(size_t)(k0 + ty + i * 8) * N + n0 + tx];
    __syncthreads();
#pragma unroll
    for (int i = 0; i < 4; i++)
        out[(size_t)(n0 + ty + i * 8) * K + k0 + tx] = (__bf16)tile[tx][ty + i * 8];
}

// ---------------- GEMM: C[M,N] = A[M,K] @ Bt[N,K]^T  (m97 structure) ----------------
// ABF16: A is bf16 (global_load_lds); else A is f32 (reg-staged, padded LDS)
// EPI 0: bf16 store C*scale   1: f32 store C+res   2: bf16 store relu(C+bias)
// EPI 3: f32 store C+bias+res
template <int EPI, bool ABF16>
__global__ __launch_bounds__(256) void gemm_bt(const void* __restrict__ Av,
                                               const __bf16* __restrict__ Bt,
                                               void* __restrict__ Cout,
                                               const float* __restrict__ bias,
                                               const float* __restrict__ res,
                                               int M, int N, int K, float scale, int nbx) {
    constexpr int LDA = ABF16 ? 32 : 40;
    __shared__ __bf16 As[128 * 40];
    __shared__ __bf16 Bs[128 * 32];

    // bijective XCD swizzle (grid size is always a multiple of 8 here)
    int q = gridDim.x >> 3;
    int orig = blockIdx.x;
    int swz = (orig & 7) * q + (orig >> 3);
    int bn = (swz % nbx) * 128;
    int bm = (swz / nbx) * 128;

    int t = threadIdx.x;
    int lane = t & 63, wave = t >> 6;
    int wm = (wave >> 1) * 64, wn = (wave & 1) * 64;
    int l16 = lane & 15, l4 = lane >> 4;

    f32x4 acc[4][4];
#pragma unroll
    for (int m = 0; m < 4; m++)
#pragma unroll
        for (int n = 0; n < 4; n++) acc[m][n] = (f32x4){0.f, 0.f, 0.f, 0.f};

    int srow = t >> 2;           // 0..63 (global_load_lds staging row)
    int scol = (t & 3) * 8;      // k-offset (8 bf16 = 16 B)
    int ar = t >> 1, ak = (t & 1) * 16;  // f32 A staging
    const __bf16* Ab = (const __bf16*)Av;
    const float* Af = (const float*)Av;

    for (int k0 = 0; k0 < K; k0 += 32) {
        // B: async global->LDS (linear [128][32])
        gll16(Bt + (size_t)(bn + srow) * K + (k0 + scol), &Bs[wave * 512]);
        gll16(Bt + (size_t)(bn + 64 + srow) * K + (k0 + scol), &Bs[2048 + wave * 512]);
        if constexpr (ABF16) {
            gll16(Ab + (size_t)(bm + srow) * K + (k0 + scol), &As[wave * 512]);
            gll16(Ab + (size_t)(bm + 64 + srow) * K + (k0 + scol), &As[2048 + wave * 512]);
        } else {
            const float* ap = Af + (size_t)(bm + ar) * K + k0 + ak;
            float4 f0 = ((const float4*)ap)[0];
            float4 f1 = ((const float4*)ap)[1];
            float4 f2 = ((const float4*)ap)[2];
            float4 f3 = ((const float4*)ap)[3];
            float ta[16] = {f0.x, f0.y, f0.z, f0.w, f1.x, f1.y, f1.z, f1.w,
                            f2.x, f2.y, f2.z, f2.w, f3.x, f3.y, f3.z, f3.w};
            bf16x8 v0, v1;
#pragma unroll
            for (int j = 0; j < 8; j++) { v0[j] = (__bf16)ta[j]; v1[j] = (__bf16)ta[j + 8]; }
            *(bf16x8*)&As[ar * 40 + ak] = v0;
            *(bf16x8*)&As[ar * 40 + ak + 8] = v1;
        }
        __syncthreads();

        bf16x8 af[4], bfr[4];
#pragma unroll
        for (int m = 0; m < 4; m++) af[m] = *(const bf16x8*)&As[(wm + m * 16 + l16) * LDA + l4 * 8];
#pragma unroll
        for (int n = 0; n < 4; n++) bfr[n] = *(const bf16x8*)&Bs[(wn + n * 16 + l16) * 32 + l4 * 8];
#pragma unroll
        for (int m = 0; m < 4; m++)
#pragma unroll
            for (int n = 0; n < 4; n++) acc[m][n] = MFMA16(af[m], bfr[n], acc[m][n]);
        __syncthreads();
    }

#pragma unroll
    for (int m = 0; m < 4; m++) {
#pragma unroll
        for (int r = 0; r < 4; r++) {
            int row = bm + wm + m * 16 + l4 * 4 + r;
#pragma unroll
            for (int n = 0; n < 4; n++) {
                int col = bn + wn + n * 16 + l16;
                float c = acc[m][n][r];
                size_t idx = (size_t)row * N + col;
                if (EPI == 0) {
                    ((__bf16*)Cout)[idx] = (__bf16)(c * scale);
                } else if (EPI == 1) {
                    ((float*)Cout)[idx] = c + res[idx];
                } else if (EPI == 2) {
                    ((__bf16*)Cout)[idx] = (__bf16)fmaxf(c + bias[col], 0.0f);
                } else {
                    ((float*)Cout)[idx] = c + bias[col] + res[idx];
                }
            }
        }
    }
}

// ---------------- fused masked attention (flash-style, online softmax) ----------------
// grid = (32 = b*H, 16 q-blocks), block = 512 (2 key-groups x 4 waves x 16 queries)
// PKV layout: [L*b*1024 rows][2048] bf16, K at cols [0,1024), V at cols [1024,2048)
#define LKV 5120
#define KHALF 2560
#define CK 64
#define NCH 40
__global__ __launch_bounds__(512, 4) void attn_kernel(const __bf16* __restrict__ Pq,
                                                      const __bf16* __restrict__ PKV,
                                                      const unsigned char* __restrict__ mask,
                                                      __bf16* __restrict__ ctx) {
    int bh = blockIdx.x;
    int b = bh >> 4, h = bh & 15;
    int wave = threadIdx.x >> 6, lane = threadIdx.x & 63;
    int grp = wave >> 2, wv = wave & 3;
    int l16 = lane & 15, l4 = lane >> 4;
    int q0 = blockIdx.y * 64 + wv * 16;

    __shared__ __bf16 Ks[2][64][72];   // [grp][key][dh]
    __shared__ __bf16 Vt[2][64][72];   // [grp][dh][key ^ ((dh>>3)<<3)]  (swizzled)
    __shared__ __bf16 Ps[8][16][72];   // per-wave P [q][key]

    bf16x8 qf[2];
    {
        const __bf16* pqrow = Pq + (size_t)(b * 1024 + q0 + l16) * 1024 + h * 64;
        qf[0] = *(const bf16x8*)(pqrow + l4 * 8);
        qf[1] = *(const bf16x8*)(pqrow + 32 + l4 * 8);
    }

    f32x4 acc[4];
#pragma unroll
    for (int n = 0; n < 4; n++) acc[n] = (f32x4){0.f, 0.f, 0.f, 0.f};
    float mrow[4] = {-1e30f, -1e30f, -1e30f, -1e30f};
    float lrow[4] = {0.f, 0.f, 0.f, 0.f};

    const unsigned char* mp = mask + (size_t)b * (1024u * 1024u);

    int tl = threadIdx.x & 255;
    int skey = tl >> 2;
    int sd0 = (tl & 3) << 4;
    int kgbase = grp * KHALF;

    bf16x8 rk0, rk1, rv0, rv1;
    {
        int kg = kgbase + skey;
        int lidx = kg >> 10, i = kg & 1023;
        size_t off = ((size_t)(lidx * 2048 + b * 1024 + i) << 11) + h * 64 + sd0;
        rk0 = *(const bf16x8*)(PKV + off);
        rk1 = *(const bf16x8*)(PKV + off + 8);
        rv0 = *(const bf16x8*)(PKV + off + 1024);
        rv1 = *(const bf16x8*)(PKV + off + 1032);
    }

    for (int t = 0; t < NCH; t++) {
        *(bf16x8*)&Ks[grp][skey][sd0] = rk0;
        *(bf16x8*)&Ks[grp][skey][sd0 + 8] = rk1;
#pragma unroll
        for (int j = 0; j < 8; j++) {
            int row = sd0 + j;
            Vt[grp][row][skey ^ ((row >> 3) << 3)] = rv0[j];
            int row2 = sd0 + 8 + j;
            Vt[grp][row2][skey ^ ((row2 >> 3) << 3)] = rv1[j];
        }
        __syncthreads();

        if (t + 1 < NCH) {
            int kg = kgbase + (t + 1) * CK + skey;
            int lidx = kg >> 10, i = kg & 1023;
            size_t off = ((size_t)(lidx * 2048 + b * 1024 + i) << 11) + h * 64 + sd0;
            rk0 = *(const bf16x8*)(PKV + off);
            rk1 = *(const bf16x8*)(PKV + off + 8);
            rv0 = *(const bf16x8*)(PKV + off + 1024);
            rv1 = *(const bf16x8*)(PKV + off + 1032);
        }

        f32x4 s[4];
#pragma unroll
        for (int tile = 0; tile < 4; tile++) {
            s[tile] = (f32x4){0.f, 0.f, 0.f, 0.f};
            bf16x8 ka = *(const bf16x8*)&Ks[grp][tile * 16 + l16][l4 * 8];
            bf16x8 kb = *(const bf16x8*)&Ks[grp][tile * 16 + l16][32 + l4 * 8];
            s[tile] = MFMA16(qf[0], ka, s[tile]);
            s[tile] = MFMA16(qf[1], kb, s[tile]);
        }

        int kloc = (kgbase + t * CK) & 1023;
#pragma unroll
        for (int r = 0; r < 4; r++) {
            const unsigned char* mq = mp + (size_t)(q0 + l4 * 4 + r) * 1024 + kloc + l16;
            float s0r = s[0][r]; if (mq[0])  s0r = -1e30f;
            float s1r = s[1][r]; if (mq[16]) s1r = -1e30f;
            float s2r = s[2][r]; if (mq[32]) s2r = -1e30f;
            float s3r = s[3][r]; if (mq[48]) s3r = -1e30f;
            float vmax = fmaxf(fmaxf(s0r, s1r), fmaxf(s2r, s3r));
#pragma unroll
            for (int off = 1; off < 16; off <<= 1) vmax = fmaxf(vmax, __shfl_xor(vmax, off));
            float mnew = fmaxf(mrow[r], vmax);
            if (mnew > mrow[r]) {
                float sc = __expf(mrow[r] - mnew);
                lrow[r] *= sc;
#pragma unroll
                for (int n = 0; n < 4; n++) acc[n][r] *= sc;
                mrow[r] = mnew;
            }
            float p0 = __expf(s0r - mnew);
            float p1 = __expf(s1r - mnew);
            float p2 = __expf(s2r - mnew);
            float p3 = __expf(s3r - mnew);
            float rsum = (p0 + p1) + (p2 + p3);
#pragma unroll
            for (int off = 1; off < 16; off <<= 1) rsum += __shfl_xor(rsum, off);
            lrow[r] += rsum;
            Ps[wave][l4 * 4 + r][l16] = (__bf16)p0;
            Ps[wave][l4 * 4 + r][16 + l16] = (__bf16)p1;
            Ps[wave][l4 * 4 + r][32 + l16] = (__bf16)p2;
            Ps[wave][l4 * 4 + r][48 + l16] = (__bf16)p3;
        }

#pragma unroll
        for (int kk = 0; kk < 2; kk++) {
            bf16x8 pf = *(const bf16x8*)&Ps[wave][l16][kk * 32 + l4 * 8];
#pragma unroll
            for (int n = 0; n < 4; n++) {
                int row = n * 16 + l16;
                int colblk = (kk * 32 + l4 * 8) ^ ((row >> 3) << 3);
                bf16x8 vf = *(const bf16x8*)&Vt[grp][row][colblk];
                acc[n] = MFMA16(pf, vf, acc[n]);
            }
        }
        __syncthreads();
    }

    // ---- in-block merge of the two key-groups ----
    float* exAcc = (float*)&Ks[0][0][0];
    float* exM = (float*)&Vt[0][0][0];
    float* exL = exM + 64;
    if (grp == 1) {
#pragma unroll
        for (int n = 0; n < 4; n++)
#pragma unroll
            for (int r = 0; r < 4; r++)
                exAcc[(wv * 16 + l4 * 4 + r) * 64 + n * 16 + l16] = acc[n][r];
        if (l16 == 0) {
#pragma unroll
            for (int r = 0; r < 4; r++) {
                exM[wv * 16 + l4 * 4 + r] = mrow[r];
                exL[wv * 16 + l4 * 4 + r] = lrow[r];
            }
        }
    }
    __syncthreads();
    if (grp == 0) {
#pragma unroll
        for (int r = 0; r < 4; r++) {
            int qi = l4 * 4 + r;
            float m1 = exM[wv * 16 + qi], l1 = exL[wv * 16 + qi];
            float M = fmaxf(mrow[r], m1);
            float e0 = __expf(mrow[r] - M), e1 = __expf(m1 - M);
            float inv = 1.0f / (lrow[r] * e0 + l1 * e1);
            int qq = q0 + qi;
            __bf16* crow = ctx + ((size_t)(b * 1024 + qq) << 10) + h * 64;
#pragma unroll
            for (int n = 0; n < 4; n++)
                crow[n * 16 + l16] = (__bf16)((acc[n][r] * e0 +
                                               exAcc[(wv * 16 + qi) * 64 + n * 16 + l16] * e1) * inv);
        }
    }
}

// ---------------- launcher ----------------
extern "C" void kernel_launch(void* const* d_in, const int* in_sizes, int n_in,
                              void* d_out, int out_size, void* d_ws, size_t ws_size,
                              hipStream_t stream) {
    const float* x = (const float*)d_in[0];
    const float* memory_bank = (const float*)d_in[1];
    const unsigned char* attn_mask = (const unsigned char*)d_in[2];
    const float* ln1_g = (const float*)d_in[3];
    const float* ln1_b = (const float*)d_in[4];
    const float* Wq = (const float*)d_in[5];
    const float* Wk = (const float*)d_in[6];
    const float* Wv = (const float*)d_in[7];
    const float* Wo = (const float*)d_in[8];
    const float* ln2_g = (const float*)d_in[9];
    const float* ln2_b = (const float*)d_in[10];
    const float* W1 = (const float*)d_in[11];
    const float* b1 = (const float*)d_in[12];
    const float* W2 = (const float*)d_in[13];
    const float* b2 = (const float*)d_in[14];

    float* out = (float*)d_out;                 // [2,1024,1024]
    float* mem_out = out + 2097152;             // [5,2,1024,1024]
    float* q_out = mem_out + 4 * 2097152;       // mem[4] = LN1(x)

    char* ws = (char*)d_ws;
    // phase A (through attention):
    __bf16* PKV = (__bf16*)ws;                       // [0, 40MB)  [10240][2048]
    __bf16* Pq = (__bf16*)(ws + (40ull << 20));      // [40, 44MB) [2048][1024]
    __bf16* Wq_t = (__bf16*)(ws + (44ull << 20));    // [44, 46MB)
    __bf16* Wkv_t = (__bf16*)(ws + (46ull << 20));   // [46, 50MB) [2048][1024]
    __bf16* ctx = (__bf16*)(ws + (44ull << 20));     // [44, 48MB) (Wq_t/Wkv_t dead)
    // phase B (after attention, PKV/Pq dead):
    __bf16* Wo_t = (__bf16*)ws;                      // [0, 2MB)
    __bf16* W1_t = (__bf16*)(ws + (2ull << 20));     // [2, 10MB)  [4096][1024]
    __bf16* W2_t = (__bf16*)(ws + (10ull << 20));    // [10, 18MB) [1024][4096]
    float* x2 = (float*)(ws + (18ull << 20));        // [18, 26MB)
    __bf16* fln = (__bf16*)(ws + (26ull << 20));     // [26, 30MB)
    __bf16* h1 = (__bf16*)(ws + (30ull << 20));      // [30, 46MB) [2048][4096]

    // 1. mem concat: copy bank + LN1(x) as layer 4
    copy_kernel<<<2048, 256, 0, stream>>>(memory_bank, mem_out, 2097152);
    ln_kernel<<<2048, 256, 0, stream>>>(x, ln1_g, ln1_b, q_out, nullptr);

    // 2. weight transposes (bf16 [N][K])
    transpose_conv_kernel<<<dim3(32, 32), 256, 0, stream>>>(Wq, Wq_t, 1024, 1024);
    transpose_conv_kernel<<<dim3(32, 32), 256, 0, stream>>>(Wk, Wkv_t, 1024, 1024);
    transpose_conv_kernel<<<dim3(32, 32), 256, 0, stream>>>(Wv, Wkv_t + 1024 * 1024, 1024, 1024);

    // 3. projections (bf16 outputs): Pq = ln1(x)@Wq * 0.125 ; PKV = mem@[Wk|Wv]
    gemm_bt<0, false><<<128, 256, 0, stream>>>(q_out, Wq_t, Pq, nullptr, nullptr,
                                               2048, 1024, 1024, 0.125f, 8);
    gemm_bt<0, false><<<1280, 256, 0, stream>>>(mem_out, Wkv_t, PKV, nullptr, nullptr,
                                                10240, 2048, 1024, 1.0f, 16);

    // 4. attention -> ctx (bf16)
    attn_kernel<<<dim3(32, 16), 512, 0, stream>>>(Pq, PKV, attn_mask, ctx);

    // 5. late weight transposes (into freed PKV region)
    transpose_conv_kernel<<<dim3(32, 32), 256, 0, stream>>>(Wo, Wo_t, 1024, 1024);
    transpose_conv_kernel<<<dim3(128, 32), 256, 0, stream>>>(W1, W1_t, 1024, 4096);
    transpose_conv_kernel<<<dim3(32, 128), 256, 0, stream>>>(W2, W2_t, 4096, 1024);

    // 6. Wo + residual -> x2 (f32)
    gemm_bt<1, true><<<128, 256, 0, stream>>>(ctx, Wo_t, x2, nullptr, x,
                                              2048, 1024, 1024, 1.0f, 8);
    // 7. FFN
    ln_kernel<<<2048, 256, 0, stream>>>(x2, ln2_g, ln2_b, nullptr, fln);
    gemm_bt<2, true><<<512, 256, 0, stream>>>(fln, W1_t, h1, b1, nullptr,
                                              2048, 4096, 1024, 1.0f, 32);
    gemm_bt<3, true><<<128, 256, 0, stream>>>(h1, W2_t, out, b2, x2,
                                              2048, 1024, 4096, 1.0f, 8);
}

// Round 5
// 400.727 us; speedup vs baseline: 2.0984x; 1.2019x over previous
//
#include <hip/hip_runtime.h>
#include <hip/hip_bf16.h>

typedef __attribute__((ext_vector_type(8))) __bf16 bf16x8;
typedef __attribute__((ext_vector_type(4))) __bf16 bf16x4;
typedef __attribute__((ext_vector_type(4))) float f32x4;

#define MFMA16(a, b, c) __builtin_amdgcn_mfma_f32_16x16x32_bf16((a), (b), (c), 0, 0, 0)

__device__ __forceinline__ void gll16(const void* g, void* l) {
    __builtin_amdgcn_global_load_lds((const __attribute__((address_space(1))) void*)g,
                                     (__attribute__((address_space(3))) void*)l,
                                     16, 0, 0);
}

// ---------------- copy kernel (memory_bank -> d_out.mem[0:4]) ----------------
__global__ void copy_kernel(const float* __restrict__ in, float* __restrict__ out, int n4) {
    int i = blockIdx.x * blockDim.x + threadIdx.x;
    int stride = gridDim.x * blockDim.x;
    const float4* i4 = (const float4*)in;
    float4* o4 = (float4*)out;
    for (; i < n4; i += stride) o4[i] = i4[i];
}

// ---------------- LayerNorm (1024 cols, one block per row); f32 and/or bf16 out ----------------
__global__ __launch_bounds__(256) void ln_kernel(const float* __restrict__ x,
                                                 const float* __restrict__ g,
                                                 const float* __restrict__ bta,
                                                 float* __restrict__ outf,
                                                 __bf16* __restrict__ outb) {
    int row = blockIdx.x;
    const float4 v = ((const float4*)(x + (size_t)row * 1024))[threadIdx.x];
    float s = v.x + v.y + v.z + v.w;
    float s2 = v.x * v.x + v.y * v.y + v.z * v.z + v.w * v.w;
#pragma unroll
    for (int off = 1; off < 64; off <<= 1) {
        s += __shfl_xor(s, off);
        s2 += __shfl_xor(s2, off);
    }
    __shared__ float rs[4], rs2[4];
    int wv = threadIdx.x >> 6;
    if ((threadIdx.x & 63) == 0) { rs[wv] = s; rs2[wv] = s2; }
    __syncthreads();
    s = rs[0] + rs[1] + rs[2] + rs[3];
    s2 = rs2[0] + rs2[1] + rs2[2] + rs2[3];
    float mean = s * (1.0f / 1024.0f);
    float var = s2 * (1.0f / 1024.0f) - mean * mean;
    float rstd = rsqrtf(var + 1e-5f);
    float4 gg = ((const float4*)g)[threadIdx.x];
    float4 bb = ((const float4*)bta)[threadIdx.x];
    float4 o;
    o.x = (v.x - mean) * rstd * gg.x + bb.x;
    o.y = (v.y - mean) * rstd * gg.y + bb.y;
    o.z = (v.z - mean) * rstd * gg.z + bb.z;
    o.w = (v.w - mean) * rstd * gg.w + bb.w;
    if (outf) ((float4*)(outf + (size_t)row * 1024))[threadIdx.x] = o;
    if (outb) {
        bf16x4 ob = {(__bf16)o.x, (__bf16)o.y, (__bf16)o.z, (__bf16)o.w};
        ((bf16x4*)(outb + (size_t)row * 1024))[threadIdx.x] = ob;
    }
}

// ---------------- transpose+convert: in f32 [K][N] -> out bf16 [N][K] ----------------
__global__ __launch_bounds__(256) void transpose_conv_kernel(const float* __restrict__ in,
                                                             __bf16* __restrict__ out,
                                                             int K, int N) {
    __shared__ float tile[32][33];
    int n0 = blockIdx.x * 32, k0 = blockIdx.y * 32;
    int tx = threadIdx.x & 31, ty = threadIdx.x >> 5;  // ty 0..7
#pragma unroll
    for (int i = 0; i < 4; i++)
        tile[ty + i * 8][tx] = in[(size_t)(k0 + ty + i * 8) * N + n0 + tx];
    __syncthreads();
#pragma unroll
    for (int i = 0; i < 4; i++)
        out[(size_t)(n0 + ty + i * 8) * K + k0 + tx] = (__bf16)tile[tx][ty + i * 8];
}

// ---------------- GEMM: C[M,N] = A[M,K] @ Bt[N,K]^T  (m97 structure) ----------------
template <int EPI, bool ABF16>
__global__ __launch_bounds__(256) void gemm_bt(const void* __restrict__ Av,
                                               const __bf16* __restrict__ Bt,
                                               void* __restrict__ Cout,
                                               const float* __restrict__ bias,
                                               const float* __restrict__ res,
                                               int M, int N, int K, float scale, int nbx) {
    constexpr int LDA = ABF16 ? 32 : 40;
    __shared__ __bf16 As[128 * 40];
    __shared__ __bf16 Bs[128 * 32];

    int q = gridDim.x >> 3;
    int orig = blockIdx.x;
    int swz = (orig & 7) * q + (orig >> 3);
    int bn = (swz % nbx) * 128;
    int bm = (swz / nbx) * 128;

    int t = threadIdx.x;
    int lane = t & 63, wave = t >> 6;
    int wm = (wave >> 1) * 64, wn = (wave & 1) * 64;
    int l16 = lane & 15, l4 = lane >> 4;

    f32x4 acc[4][4];
#pragma unroll
    for (int m = 0; m < 4; m++)
#pragma unroll
        for (int n = 0; n < 4; n++) acc[m][n] = (f32x4){0.f, 0.f, 0.f, 0.f};

    int srow = t >> 2;
    int scol = (t & 3) * 8;
    int ar = t >> 1, ak = (t & 1) * 16;
    const __bf16* Ab = (const __bf16*)Av;
    const float* Af = (const float*)Av;

    for (int k0 = 0; k0 < K; k0 += 32) {
        gll16(Bt + (size_t)(bn + srow) * K + (k0 + scol), &Bs[wave * 512]);
        gll16(Bt + (size_t)(bn + 64 + srow) * K + (k0 + scol), &Bs[2048 + wave * 512]);
        if constexpr (ABF16) {
            gll16(Ab + (size_t)(bm + srow) * K + (k0 + scol), &As[wave * 512]);
            gll16(Ab + (size_t)(bm + 64 + srow) * K + (k0 + scol), &As[2048 + wave * 512]);
        } else {
            const float* ap = Af + (size_t)(bm + ar) * K + k0 + ak;
            float4 f0 = ((const float4*)ap)[0];
            float4 f1 = ((const float4*)ap)[1];
            float4 f2 = ((const float4*)ap)[2];
            float4 f3 = ((const float4*)ap)[3];
            float ta[16] = {f0.x, f0.y, f0.z, f0.w, f1.x, f1.y, f1.z, f1.w,
                            f2.x, f2.y, f2.z, f2.w, f3.x, f3.y, f3.z, f3.w};
            bf16x8 v0, v1;
#pragma unroll
            for (int j = 0; j < 8; j++) { v0[j] = (__bf16)ta[j]; v1[j] = (__bf16)ta[j + 8]; }
            *(bf16x8*)&As[ar * 40 + ak] = v0;
            *(bf16x8*)&As[ar * 40 + ak + 8] = v1;
        }
        __syncthreads();

        bf16x8 af[4], bfr[4];
#pragma unroll
        for (int m = 0; m < 4; m++) af[m] = *(const bf16x8*)&As[(wm + m * 16 + l16) * LDA + l4 * 8];
#pragma unroll
        for (int n = 0; n < 4; n++) bfr[n] = *(const bf16x8*)&Bs[(wn + n * 16 + l16) * 32 + l4 * 8];
#pragma unroll
        for (int m = 0; m < 4; m++)
#pragma unroll
            for (int n = 0; n < 4; n++) acc[m][n] = MFMA16(af[m], bfr[n], acc[m][n]);
        __syncthreads();
    }

#pragma unroll
    for (int m = 0; m < 4; m++) {
#pragma unroll
        for (int r = 0; r < 4; r++) {
            int row = bm + wm + m * 16 + l4 * 4 + r;
#pragma unroll
            for (int n = 0; n < 4; n++) {
                int col = bn + wn + n * 16 + l16;
                float c = acc[m][n][r];
                size_t idx = (size_t)row * N + col;
                if (EPI == 0) {
                    ((__bf16*)Cout)[idx] = (__bf16)(c * scale);
                } else if (EPI == 1) {
                    ((float*)Cout)[idx] = c + res[idx];
                } else if (EPI == 2) {
                    ((__bf16*)Cout)[idx] = (__bf16)fmaxf(c + bias[col], 0.0f);
                } else {
                    ((float*)Cout)[idx] = c + bias[col] + res[idx];
                }
            }
        }
    }
}

// ---------------- fused masked attention v3: swapped-operand, per-lane softmax ----------------
// grid = (32 = b*H, 16 q-blocks), block = 512 (2 key-groups x 4 waves x 16 queries)
// PKV layout: [L*b*1024 rows][2048] bf16, K at cols [0,1024), V at cols [1024,2048)
#define LKV 5120
#define KHALF 2560
#define CK 64
#define NCH 40
__global__ __launch_bounds__(512, 4) void attn_kernel(const __bf16* __restrict__ Pq,
                                                      const __bf16* __restrict__ PKV,
                                                      const unsigned char* __restrict__ mask,
                                                      __bf16* __restrict__ ctx) {
    int bh = blockIdx.x;
    int b = bh >> 4, h = bh & 15;
    int wave = threadIdx.x >> 6, lane = threadIdx.x & 63;
    int grp = wave >> 2, wv = wave & 3;
    int l16 = lane & 15, l4 = lane >> 4;
    int q0 = blockIdx.y * 64 + wv * 16;

    __shared__ __bf16 Ks[2][64][72];   // [grp][key][dh]
    __shared__ __bf16 Vt[2][64][72];   // [grp][dh][key ^ ((dh>>3)<<3)]  (swizzled)
    __shared__ __bf16 Ps[8][16][72];   // per-wave P [q][key]

    const f32x4 fzero = {0.f, 0.f, 0.f, 0.f};

    // Q as B-fragment: col = q = l16, k = dh slice l4*8+j
    bf16x8 qf[2];
    {
        const __bf16* pqrow = Pq + (size_t)(b * 1024 + q0 + l16) * 1024 + h * 64;
        qf[0] = *(const bf16x8*)(pqrow + l4 * 8);
        qf[1] = *(const bf16x8*)(pqrow + 32 + l4 * 8);
    }

    // accT[n][r]: q = l16, dh = n*16 + l4*4 + r  (swapped-PV C layout)
    f32x4 accT[4];
#pragma unroll
    for (int n = 0; n < 4; n++) accT[n] = fzero;
    float m = 0.0f;      // defer-max: scores are tiny; rescale branch ~never taken
    float lsum = 0.0f;   // per-lane partial (this lane's key subset); reduced at end

    // per-lane mask row (q = l16)
    const unsigned char* mrow_p = mask + (size_t)b * (1024u * 1024u) + (size_t)(q0 + l16) * 1024;

    int tl = threadIdx.x & 255;
    int skey = tl >> 2;
    int sd0 = (tl & 3) << 4;
    int kgbase = grp * KHALF;

    bf16x8 rk0, rk1, rv0, rv1;
    unsigned int mk[4], mkn[4];
    {
        int kg = kgbase + skey;
        int lidx = kg >> 10, i = kg & 1023;
        size_t off = ((size_t)(lidx * 2048 + b * 1024 + i) << 11) + h * 64 + sd0;
        rk0 = *(const bf16x8*)(PKV + off);
        rk1 = *(const bf16x8*)(PKV + off + 8);
        rv0 = *(const bf16x8*)(PKV + off + 1024);
        rv1 = *(const bf16x8*)(PKV + off + 1032);
        int kloc = kgbase & 1023;
#pragma unroll
        for (int tile = 0; tile < 4; tile++)
            mk[tile] = *(const unsigned int*)(mrow_p + kloc + tile * 16 + l4 * 4);
    }

    for (int t = 0; t < NCH; t++) {
        // ---- staged regs -> LDS ----
        *(bf16x8*)&Ks[grp][skey][sd0] = rk0;
        *(bf16x8*)&Ks[grp][skey][sd0 + 8] = rk1;
#pragma unroll
        for (int j = 0; j < 8; j++) {
            int row = sd0 + j;
            Vt[grp][row][skey ^ ((row >> 3) << 3)] = rv0[j];
            int row2 = sd0 + 8 + j;
            Vt[grp][row2][skey ^ ((row2 >> 3) << 3)] = rv1[j];
        }
        __syncthreads();

        // ---- prefetch next chunk (K/V regs + mask dwords) ----
        if (t + 1 < NCH) {
            int kg = kgbase + (t + 1) * CK + skey;
            int lidx = kg >> 10, i = kg & 1023;
            size_t off = ((size_t)(lidx * 2048 + b * 1024 + i) << 11) + h * 64 + sd0;
            rk0 = *(const bf16x8*)(PKV + off);
            rk1 = *(const bf16x8*)(PKV + off + 8);
            rv0 = *(const bf16x8*)(PKV + off + 1024);
            rv1 = *(const bf16x8*)(PKV + off + 1032);
            int kloc = (kgbase + (t + 1) * CK) & 1023;
#pragma unroll
            for (int tile = 0; tile < 4; tile++)
                mkn[tile] = *(const unsigned int*)(mrow_p + kloc + tile * 16 + l4 * 4);
        }

        // ---- QK^T swapped: s[tile][r] = S[key = tile*16+l4*4+r][q = l16] ----
        f32x4 s[4];
        __builtin_amdgcn_s_setprio(1);
#pragma unroll
        for (int tile = 0; tile < 4; tile++) {
            bf16x8 ka = *(const bf16x8*)&Ks[grp][tile * 16 + l16][l4 * 8];
            bf16x8 kb = *(const bf16x8*)&Ks[grp][tile * 16 + l16][32 + l4 * 8];
            f32x4 sz = fzero;
            sz = MFMA16(ka, qf[0], sz);
            sz = MFMA16(kb, qf[1], sz);
            s[tile] = sz;
        }
        __builtin_amdgcn_s_setprio(0);

        // ---- per-lane online softmax (q = l16), defer-max THR=8 ----
        float pa = fmaxf(fmaxf(s[0][0], s[0][1]), fmaxf(s[0][2], s[0][3]));
        float pb = fmaxf(fmaxf(s[1][0], s[1][1]), fmaxf(s[1][2], s[1][3]));
        float pc = fmaxf(fmaxf(s[2][0], s[2][1]), fmaxf(s[2][2], s[2][3]));
        float pd = fmaxf(fmaxf(s[3][0], s[3][1]), fmaxf(s[3][2], s[3][3]));
        float pmax = fmaxf(fmaxf(pa, pb), fmaxf(pc, pd));
        pmax = fmaxf(pmax, __shfl_xor(pmax, 16));
        pmax = fmaxf(pmax, __shfl_xor(pmax, 32));
        if (__builtin_expect(pmax > m + 8.0f, 0)) {
            float sc = __expf(m - pmax);
            lsum *= sc;
#pragma unroll
            for (int n = 0; n < 4; n++) accT[n] *= sc;
            m = pmax;
        }
        float psum = 0.0f;
#pragma unroll
        for (int tile = 0; tile < 4; tile++) {
            bf16x4 pk_;
#pragma unroll
            for (int r = 0; r < 4; r++) {
                float e = __expf(s[tile][r] - m);
                e = ((mk[tile] >> (r * 8)) & 255u) ? 0.0f : e;
                psum += e;
                pk_[r] = (__bf16)e;
            }
            *(bf16x4*)&Ps[wave][l16][tile * 16 + l4 * 4] = pk_;
        }
        lsum += psum;
#pragma unroll
        for (int tile = 0; tile < 4; tile++) mk[tile] = mkn[tile];

        // ---- PV swapped: accT[n] += V^T @ P^T ----
        __builtin_amdgcn_s_setprio(1);
#pragma unroll
        for (int kk = 0; kk < 2; kk++) {
            bf16x8 pf = *(const bf16x8*)&Ps[wave][l16][kk * 32 + l4 * 8];
#pragma unroll
            for (int n = 0; n < 4; n++) {
                int row = n * 16 + l16;
                int colblk = (kk * 32 + l4 * 8) ^ ((row >> 3) << 3);
                bf16x8 vf = *(const bf16x8*)&Vt[grp][row][colblk];
                accT[n] = MFMA16(vf, pf, accT[n]);
            }
        }
        __builtin_amdgcn_s_setprio(0);
        __syncthreads();
    }

    // ---- reduce partial l across the 4 key-subset replicas (same q) ----
    lsum += __shfl_xor(lsum, 16);
    lsum += __shfl_xor(lsum, 32);

    // ---- in-block merge of the two key-groups ----
    float* exAcc = (float*)&Ks[0][0][0];   // [64 q][68] f32 = 17408 B (fits in Ks)
    float* exM = (float*)&Vt[0][0][0];
    float* exL = exM + 64;
    if (grp == 1) {
#pragma unroll
        for (int n = 0; n < 4; n++)
            *(f32x4*)&exAcc[(wv * 16 + l16) * 68 + n * 16 + l4 * 4] = accT[n];
        if (l4 == 0) { exM[wv * 16 + l16] = m; exL[wv * 16 + l16] = lsum; }
    }
    __syncthreads();
    if (grp == 0) {
        int qi = wv * 16 + l16;
        float m1 = exM[qi], l1 = exL[qi];
        float M = fmaxf(m, m1);
        float e0 = __expf(m - M), e1 = __expf(m1 - M);
        float inv = 1.0f / (lsum * e0 + l1 * e1);
        __bf16* crow = ctx + ((size_t)(b * 1024 + q0 + l16) << 10) + h * 64;
#pragma unroll
        for (int n = 0; n < 4; n++) {
            f32x4 a1 = *(const f32x4*)&exAcc[qi * 68 + n * 16 + l4 * 4];
            bf16x4 o;
#pragma unroll
            for (int r = 0; r < 4; r++) o[r] = (__bf16)((accT[n][r] * e0 + a1[r] * e1) * inv);
            *(bf16x4*)&crow[n * 16 + l4 * 4] = o;
        }
    }
}

// ---------------- launcher ----------------
extern "C" void kernel_launch(void* const* d_in, const int* in_sizes, int n_in,
                              void* d_out, int out_size, void* d_ws, size_t ws_size,
                              hipStream_t stream) {
    const float* x = (const float*)d_in[0];
    const float* memory_bank = (const float*)d_in[1];
    const unsigned char* attn_mask = (const unsigned char*)d_in[2];
    const float* ln1_g = (const float*)d_in[3];
    const float* ln1_b = (const float*)d_in[4];
    const float* Wq = (const float*)d_in[5];
    const float* Wk = (const float*)d_in[6];
    const float* Wv = (const float*)d_in[7];
    const float* Wo = (const float*)d_in[8];
    const float* ln2_g = (const float*)d_in[9];
    const float* ln2_b = (const float*)d_in[10];
    const float* W1 = (const float*)d_in[11];
    const float* b1 = (const float*)d_in[12];
    const float* W2 = (const float*)d_in[13];
    const float* b2 = (const float*)d_in[14];

    float* out = (float*)d_out;                 // [2,1024,1024]
    float* mem_out = out + 2097152;             // [5,2,1024,1024]
    float* q_out = mem_out + 4 * 2097152;       // mem[4] = LN1(x)

    char* ws = (char*)d_ws;
    // phase A (through attention):
    __bf16* PKV = (__bf16*)ws;                       // [0, 40MB)  [10240][2048]
    __bf16* Pq = (__bf16*)(ws + (40ull << 20));      // [40, 44MB) [2048][1024]
    __bf16* Wq_t = (__bf16*)(ws + (44ull << 20));    // [44, 46MB)
    __bf16* Wkv_t = (__bf16*)(ws + (46ull << 20));   // [46, 50MB) [2048][1024]
    __bf16* ctx = (__bf16*)(ws + (44ull << 20));     // [44, 48MB) (Wq_t/Wkv_t dead)
    // phase B (after attention, PKV/Pq dead):
    __bf16* Wo_t = (__bf16*)ws;                      // [0, 2MB)
    __bf16* W1_t = (__bf16*)(ws + (2ull << 20));     // [2, 10MB)  [4096][1024]
    __bf16* W2_t = (__bf16*)(ws + (10ull << 20));    // [10, 18MB) [1024][4096]
    float* x2 = (float*)(ws + (18ull << 20));        // [18, 26MB)
    __bf16* fln = (__bf16*)(ws + (26ull << 20));     // [26, 30MB)
    __bf16* h1 = (__bf16*)(ws + (30ull << 20));      // [30, 46MB) [2048][4096]

    // 1. mem concat: copy bank + LN1(x) as layer 4
    copy_kernel<<<2048, 256, 0, stream>>>(memory_bank, mem_out, 2097152);
    ln_kernel<<<2048, 256, 0, stream>>>(x, ln1_g, ln1_b, q_out, nullptr);

    // 2. weight transposes (bf16 [N][K])
    transpose_conv_kernel<<<dim3(32, 32), 256, 0, stream>>>(Wq, Wq_t, 1024, 1024);
    transpose_conv_kernel<<<dim3(32, 32), 256, 0, stream>>>(Wk, Wkv_t, 1024, 1024);
    transpose_conv_kernel<<<dim3(32, 32), 256, 0, stream>>>(Wv, Wkv_t + 1024 * 1024, 1024, 1024);

    // 3. projections (bf16 outputs): Pq = ln1(x)@Wq * 0.125 ; PKV = mem@[Wk|Wv]
    gemm_bt<0, false><<<128, 256, 0, stream>>>(q_out, Wq_t, Pq, nullptr, nullptr,
                                               2048, 1024, 1024, 0.125f, 8);
    gemm_bt<0, false><<<1280, 256, 0, stream>>>(mem_out, Wkv_t, PKV, nullptr, nullptr,
                                                10240, 2048, 1024, 1.0f, 16);

    // 4. attention -> ctx (bf16)
    attn_kernel<<<dim3(32, 16), 512, 0, stream>>>(Pq, PKV, attn_mask, ctx);

    // 5. late weight transposes (into freed PKV region)
    transpose_conv_kernel<<<dim3(32, 32), 256, 0, stream>>>(Wo, Wo_t, 1024, 1024);
    transpose_conv_kernel<<<dim3(128, 32), 256, 0, stream>>>(W1, W1_t, 1024, 4096);
    transpose_conv_kernel<<<dim3(32, 128), 256, 0, stream>>>(W2, W2_t, 4096, 1024);

    // 6. Wo + residual -> x2 (f32)
    gemm_bt<1, true><<<128, 256, 0, stream>>>(ctx, Wo_t, x2, nullptr, x,
                                              2048, 1024, 1024, 1.0f, 8);
    // 7. FFN
    ln_kernel<<<2048, 256, 0, stream>>>(x2, ln2_g, ln2_b, nullptr, fln);
    gemm_bt<2, true><<<512, 256, 0, stream>>>(fln, W1_t, h1, b1, nullptr,
                                              2048, 4096, 1024, 1.0f, 32);
    gemm_bt<3, true><<<128, 256, 0, stream>>>(h1, W2_t, out, b2, x2,
                                              2048, 1024, 4096, 1.0f, 8);
}

// Round 6
// 301.711 us; speedup vs baseline: 2.7870x; 1.3282x over previous
//
#include <hip/hip_runtime.h>
#include <hip/hip_bf16.h>

typedef __attribute__((ext_vector_type(8))) __bf16 bf16x8;
typedef __attribute__((ext_vector_type(4))) __bf16 bf16x4;
typedef __attribute__((ext_vector_type(4))) float f32x4;

#define MFMA16(a, b, c) __builtin_amdgcn_mfma_f32_16x16x32_bf16((a), (b), (c), 0, 0, 0)
#define LOG2E 1.4426950408889634f

static __device__ __forceinline__ float exp2_fast(float x) {
    float r; asm("v_exp_f32 %0, %1" : "=v"(r) : "v"(x)); return r;
}

__device__ __forceinline__ void gll16(const void* g, void* l) {
    __builtin_amdgcn_global_load_lds((const __attribute__((address_space(1))) void*)g,
                                     (__attribute__((address_space(3))) void*)l,
                                     16, 0, 0);
}

// ---------------- prep: blocks [0,2048) copy bank (+bf16 dup); [2048,4096) LN1 ----------------
__global__ __launch_bounds__(256) void prep_kernel(const float* __restrict__ bank,
                                                   float* __restrict__ mem_out,
                                                   __bf16* __restrict__ membf,
                                                   const float* __restrict__ x,
                                                   const float* __restrict__ g,
                                                   const float* __restrict__ bta,
                                                   float* __restrict__ q_out,
                                                   __bf16* __restrict__ qbf) {
    __shared__ float rs[4], rs2[4];
    int blk = blockIdx.x;
    if (blk < 2048) {
        int i = blk * 256 + threadIdx.x;
        const float4* i4 = (const float4*)bank;
        float4* o4 = (float4*)mem_out;
        for (; i < 2097152; i += 2048 * 256) {
            float4 v = i4[i];
            o4[i] = v;
            if (membf) {
                bf16x4 ob = {(__bf16)v.x, (__bf16)v.y, (__bf16)v.z, (__bf16)v.w};
                ((bf16x4*)membf)[i] = ob;
            }
        }
    } else {
        int row = blk - 2048;
        const float4 v = ((const float4*)(x + (size_t)row * 1024))[threadIdx.x];
        float s = v.x + v.y + v.z + v.w;
        float s2 = v.x * v.x + v.y * v.y + v.z * v.z + v.w * v.w;
#pragma unroll
        for (int off = 1; off < 64; off <<= 1) {
            s += __shfl_xor(s, off);
            s2 += __shfl_xor(s2, off);
        }
        int wv = threadIdx.x >> 6;
        if ((threadIdx.x & 63) == 0) { rs[wv] = s; rs2[wv] = s2; }
        __syncthreads();
        s = rs[0] + rs[1] + rs[2] + rs[3];
        s2 = rs2[0] + rs2[1] + rs2[2] + rs2[3];
        float mean = s * (1.0f / 1024.0f);
        float var = s2 * (1.0f / 1024.0f) - mean * mean;
        float rstd = rsqrtf(var + 1e-5f);
        float4 gg = ((const float4*)g)[threadIdx.x];
        float4 bb = ((const float4*)bta)[threadIdx.x];
        float4 o;
        o.x = (v.x - mean) * rstd * gg.x + bb.x;
        o.y = (v.y - mean) * rstd * gg.y + bb.y;
        o.z = (v.z - mean) * rstd * gg.z + bb.z;
        o.w = (v.w - mean) * rstd * gg.w + bb.w;
        ((float4*)(q_out + (size_t)row * 1024))[threadIdx.x] = o;
        if (qbf) {
            bf16x4 ob = {(__bf16)o.x, (__bf16)o.y, (__bf16)o.z, (__bf16)o.w};
            ((bf16x4*)(qbf + (size_t)row * 1024))[threadIdx.x] = ob;
        }
    }
}

// ---------------- LayerNorm (LN2) ----------------
__global__ __launch_bounds__(256) void ln_kernel(const float* __restrict__ x,
                                                 const float* __restrict__ g,
                                                 const float* __restrict__ bta,
                                                 __bf16* __restrict__ outb) {
    int row = blockIdx.x;
    const float4 v = ((const float4*)(x + (size_t)row * 1024))[threadIdx.x];
    float s = v.x + v.y + v.z + v.w;
    float s2 = v.x * v.x + v.y * v.y + v.z * v.z + v.w * v.w;
#pragma unroll
    for (int off = 1; off < 64; off <<= 1) {
        s += __shfl_xor(s, off);
        s2 += __shfl_xor(s2, off);
    }
    __shared__ float rs[4], rs2[4];
    int wv = threadIdx.x >> 6;
    if ((threadIdx.x & 63) == 0) { rs[wv] = s; rs2[wv] = s2; }
    __syncthreads();
    s = rs[0] + rs[1] + rs[2] + rs[3];
    s2 = rs2[0] + rs2[1] + rs2[2] + rs2[3];
    float mean = s * (1.0f / 1024.0f);
    float var = s2 * (1.0f / 1024.0f) - mean * mean;
    float rstd = rsqrtf(var + 1e-5f);
    float4 gg = ((const float4*)g)[threadIdx.x];
    float4 bb = ((const float4*)bta)[threadIdx.x];
    bf16x4 ob;
    ob[0] = (__bf16)((v.x - mean) * rstd * gg.x + bb.x);
    ob[1] = (__bf16)((v.y - mean) * rstd * gg.y + bb.y);
    ob[2] = (__bf16)((v.z - mean) * rstd * gg.z + bb.z);
    ob[3] = (__bf16)((v.w - mean) * rstd * gg.w + bb.w);
    ((bf16x4*)(outb + (size_t)row * 1024))[threadIdx.x] = ob;
}

// ---------------- transpose+convert body: in f32 [K][N] -> out bf16 [N][K] ----------------
__device__ __forceinline__ void tr_body(const float* __restrict__ in, __bf16* __restrict__ out,
                                        int K, int N, int k0, int n0) {
    __shared__ float tile[32][33];
    int tx = threadIdx.x & 31, ty = threadIdx.x >> 5;
#pragma unroll
    for (int i = 0; i < 4; i++)
        tile[ty + i * 8][tx] = in[(size_t)(k0 + ty + i * 8) * N + n0 + tx];
    __syncthreads();
#pragma unroll
    for (int i = 0; i < 4; i++)
        out[(size_t)(n0 + ty + i * 8) * K + k0 + tx] = (__bf16)tile[tx][ty + i * 8];
}

__global__ __launch_bounds__(256) void tr_early(const float* __restrict__ Wq,
                                                const float* __restrict__ Wk,
                                                const float* __restrict__ Wv,
                                                __bf16* __restrict__ Wq_t,
                                                __bf16* __restrict__ Wkv_t) {
    int w = blockIdx.x;
    int sel = w >> 10, within = w & 1023;
    const float* in = (sel == 0) ? Wq : ((sel == 1) ? Wk : Wv);
    __bf16* out = (sel == 0) ? Wq_t : (Wkv_t + (size_t)(sel - 1) * 1048576);
    tr_body(in, out, 1024, 1024, (within >> 5) * 32, (within & 31) * 32);
}

__global__ __launch_bounds__(256) void tr_late(const float* __restrict__ Wo,
                                               const float* __restrict__ W1,
                                               const float* __restrict__ W2,
                                               __bf16* __restrict__ Wo_t,
                                               __bf16* __restrict__ W1_t,
                                               __bf16* __restrict__ W2_t) {
    int w = blockIdx.x;
    const float* in;
    __bf16* out;
    int K, N, k0, n0;
    if (w < 1024) {
        in = Wo; out = Wo_t; K = 1024; N = 1024; n0 = (w & 31) * 32; k0 = (w >> 5) * 32;
    } else if (w < 5120) {
        int v = w - 1024;
        in = W1; out = W1_t; K = 1024; N = 4096; n0 = (v & 127) * 32; k0 = (v >> 7) * 32;
    } else {
        int v = w - 5120;
        in = W2; out = W2_t; K = 4096; N = 1024; n0 = (v & 31) * 32; k0 = (v >> 5) * 32;
    }
    tr_body(in, out, K, N, k0, n0);
}

// ---------------- GEMM core: C[*,N] = A[*,lda] @ Bt[N,ldb]^T over klen ----------------
// EPI 0: bf16 C*scale  1: f32 C+res  2: bf16 relu(C+bias)  3: f32 C+bias+res  4: f32 C
template <int EPI, bool ABF16>
__device__ __forceinline__ void gemm_core(const void* __restrict__ Av,
                                          const __bf16* __restrict__ Bt,
                                          void* __restrict__ Cout,
                                          const float* __restrict__ bias,
                                          const float* __restrict__ res,
                                          int N, int lda, int ldb, int klen,
                                          float scale, int bm, int bn) {
    constexpr int LDA = ABF16 ? 32 : 40;
    __shared__ __bf16 As[128 * LDA];
    __shared__ __bf16 Bs[128 * 32];

    int t = threadIdx.x;
    int lane = t & 63, wave = t >> 6;
    int wm = (wave >> 1) * 64, wn = (wave & 1) * 64;
    int l16 = lane & 15, l4 = lane >> 4;

    f32x4 acc[4][4];
#pragma unroll
    for (int m = 0; m < 4; m++)
#pragma unroll
        for (int n = 0; n < 4; n++) acc[m][n] = (f32x4){0.f, 0.f, 0.f, 0.f};

    int srow = t >> 2;
    int scol = (t & 3) * 8;
    int ar = t >> 1, ak = (t & 1) * 16;
    const __bf16* Ab = (const __bf16*)Av;
    const float* Af = (const float*)Av;

    for (int k0 = 0; k0 < klen; k0 += 32) {
        gll16(Bt + (size_t)(bn + srow) * ldb + (k0 + scol), &Bs[wave * 512]);
        gll16(Bt + (size_t)(bn + 64 + srow) * ldb + (k0 + scol), &Bs[2048 + wave * 512]);
        if constexpr (ABF16) {
            gll16(Ab + (size_t)(bm + srow) * lda + (k0 + scol), &As[wave * 512]);
            gll16(Ab + (size_t)(bm + 64 + srow) * lda + (k0 + scol), &As[2048 + wave * 512]);
        } else {
            const float* ap = Af + (size_t)(bm + ar) * lda + k0 + ak;
            float4 f0 = ((const float4*)ap)[0];
            float4 f1 = ((const float4*)ap)[1];
            float4 f2 = ((const float4*)ap)[2];
            float4 f3 = ((const float4*)ap)[3];
            float ta[16] = {f0.x, f0.y, f0.z, f0.w, f1.x, f1.y, f1.z, f1.w,
                            f2.x, f2.y, f2.z, f2.w, f3.x, f3.y, f3.z, f3.w};
            bf16x8 v0, v1;
#pragma unroll
            for (int j = 0; j < 8; j++) { v0[j] = (__bf16)ta[j]; v1[j] = (__bf16)ta[j + 8]; }
            *(bf16x8*)&As[ar * 40 + ak] = v0;
            *(bf16x8*)&As[ar * 40 + ak + 8] = v1;
        }
        __syncthreads();

        bf16x8 af[4], bfr[4];
#pragma unroll
        for (int m = 0; m < 4; m++) af[m] = *(const bf16x8*)&As[(wm + m * 16 + l16) * LDA + l4 * 8];
#pragma unroll
        for (int n = 0; n < 4; n++) bfr[n] = *(const bf16x8*)&Bs[(wn + n * 16 + l16) * 32 + l4 * 8];
#pragma unroll
        for (int m = 0; m < 4; m++)
#pragma unroll
            for (int n = 0; n < 4; n++) acc[m][n] = MFMA16(af[m], bfr[n], acc[m][n]);
        __syncthreads();
    }

#pragma unroll
    for (int m = 0; m < 4; m++) {
#pragma unroll
        for (int r = 0; r < 4; r++) {
            int row = bm + wm + m * 16 + l4 * 4 + r;
#pragma unroll
            for (int n = 0; n < 4; n++) {
                int col = bn + wn + n * 16 + l16;
                float c = acc[m][n][r];
                size_t idx = (size_t)row * N + col;
                if (EPI == 0) {
                    ((__bf16*)Cout)[idx] = (__bf16)(c * scale);
                } else if (EPI == 1) {
                    ((float*)Cout)[idx] = c + res[idx];
                } else if (EPI == 2) {
                    ((__bf16*)Cout)[idx] = (__bf16)fmaxf(c + bias[col], 0.0f);
                } else if (EPI == 3) {
                    ((float*)Cout)[idx] = c + bias[col] + res[idx];
                } else {
                    ((float*)Cout)[idx] = c;
                }
            }
        }
    }
}

template <int EPI, bool ABF16>
__global__ __launch_bounds__(256) void gemm_bt(const void* __restrict__ Av,
                                               const __bf16* __restrict__ Bt,
                                               void* __restrict__ Cout,
                                               const float* __restrict__ bias,
                                               const float* __restrict__ res,
                                               int N, int K, float scale, int nbx) {
    int q = gridDim.x >> 3;
    int swz = (blockIdx.x & 7) * q + (blockIdx.x >> 3);
    int bn = (swz % nbx) * 128;
    int bm = (swz / nbx) * 128;
    gemm_core<EPI, ABF16>(Av, Bt, Cout, bias, res, N, K, K, K, scale, bm, bn);
}

// fused projections: blocks [0,1280) KV (M=10240,N=2048); [1280,1408) Pq (M=2048,N=1024)
template <bool ABF16>
__global__ __launch_bounds__(256) void gemm_proj(const void* __restrict__ Akv,
                                                 const __bf16* __restrict__ Wkv_t,
                                                 __bf16* __restrict__ PKV,
                                                 const void* __restrict__ Aq,
                                                 const __bf16* __restrict__ Wq_t,
                                                 __bf16* __restrict__ Pq) {
    int q = gridDim.x >> 3;
    int swz = (blockIdx.x & 7) * q + (blockIdx.x >> 3);
    const void* A;
    const __bf16* B;
    __bf16* C;
    int N, bm, bn;
    float sc;
    if (swz < 1280) {
        A = Akv; B = Wkv_t; C = PKV; N = 2048; sc = 1.0f;
        bn = (swz & 15) * 128; bm = (swz >> 4) * 128;
    } else {
        int p = swz - 1280;
        A = Aq; B = Wq_t; C = Pq; N = 1024; sc = 0.125f * LOG2E;
        bn = (p & 7) * 128; bm = (p >> 3) * 128;
    }
    gemm_core<0, ABF16>(A, B, C, nullptr, nullptr, N, 1024, 1024, 1024, sc, bm, bn);
}

// W2 split-K2 (big mode): blocks [0,128) K-half 0 -> pc0; [128,256) K-half 1 -> pc1
__global__ __launch_bounds__(256) void gemm_w2(const __bf16* __restrict__ h1,
                                               const __bf16* __restrict__ W2_t,
                                               float* __restrict__ pc0,
                                               float* __restrict__ pc1) {
    int q = gridDim.x >> 3;
    int swz = (blockIdx.x & 7) * q + (blockIdx.x >> 3);
    int half = swz >> 7;
    int p = swz & 127;
    int bn = (p & 7) * 128, bm = (p >> 3) * 128;
    int koff = half * 2048;
    gemm_core<4, true>(h1 + koff, W2_t + koff, half ? pc1 : pc0, nullptr, nullptr,
                       1024, 4096, 4096, 2048, 1.0f, bm, bn);
}

__global__ __launch_bounds__(256) void w2comb(const float* __restrict__ pc0,
                                              const float* __restrict__ pc1,
                                              const float* __restrict__ b2,
                                              const float* __restrict__ x2,
                                              float* __restrict__ out) {
    int i = blockIdx.x * 256 + threadIdx.x;
    float4 a = ((const float4*)pc0)[i];
    float4 b = ((const float4*)pc1)[i];
    float4 r = ((const float4*)x2)[i];
    float4 bb = ((const float4*)b2)[i & 255];
    float4 o;
    o.x = a.x + b.x + r.x + bb.x;
    o.y = a.y + b.y + r.y + bb.y;
    o.z = a.z + b.z + r.z + bb.z;
    o.w = a.w + b.w + r.w + bb.w;
    ((float4*)out)[i] = o;
}

// ---------------- fused masked attention (swapped-operand, per-lane softmax, exp2 domain) ----
#define LKV 5120
#define KHALF 2560
#define CK 64
#define NCH 40
__global__ __launch_bounds__(512, 4) void attn_kernel(const __bf16* __restrict__ Pq,
                                                      const __bf16* __restrict__ PKV,
                                                      const unsigned char* __restrict__ mask,
                                                      __bf16* __restrict__ ctx) {
    int bh = blockIdx.x;
    int b = bh >> 4, h = bh & 15;
    int wave = threadIdx.x >> 6, lane = threadIdx.x & 63;
    int grp = wave >> 2, wv = wave & 3;
    int l16 = lane & 15, l4 = lane >> 4;
    int q0 = blockIdx.y * 64 + wv * 16;

    __shared__ __bf16 Ks[2][64][72];
    __shared__ __bf16 Vt[2][64][72];
    __shared__ __bf16 Ps[8][16][72];

    const f32x4 fzero = {0.f, 0.f, 0.f, 0.f};

    bf16x8 qf[2];
    {
        const __bf16* pqrow = Pq + (size_t)(b * 1024 + q0 + l16) * 1024 + h * 64;
        qf[0] = *(const bf16x8*)(pqrow + l4 * 8);
        qf[1] = *(const bf16x8*)(pqrow + 32 + l4 * 8);
    }

    f32x4 accT[4];
#pragma unroll
    for (int n = 0; n < 4; n++) accT[n] = fzero;
    float m = 0.0f;      // log2-domain running max (defer-max, THR=8)
    float lsum = 0.0f;

    const unsigned char* mrow_p = mask + (size_t)b * (1024u * 1024u) + (size_t)(q0 + l16) * 1024;

    int tl = threadIdx.x & 255;
    int skey = tl >> 2;
    int sd0 = (tl & 3) << 4;
    int kgbase = grp * KHALF;

    bf16x8 rk0, rk1, rv0, rv1;
    unsigned int mk[4], mkn[4];
    {
        int kg = kgbase + skey;
        int lidx = kg >> 10, i = kg & 1023;
        size_t off = ((size_t)(lidx * 2048 + b * 1024 + i) << 11) + h * 64 + sd0;
        rk0 = *(const bf16x8*)(PKV + off);
        rk1 = *(const bf16x8*)(PKV + off + 8);
        rv0 = *(const bf16x8*)(PKV + off + 1024);
        rv1 = *(const bf16x8*)(PKV + off + 1032);
        int kloc = kgbase & 1023;
#pragma unroll
        for (int tile = 0; tile < 4; tile++)
            mk[tile] = *(const unsigned int*)(mrow_p + kloc + tile * 16 + l4 * 4);
    }

    for (int t = 0; t < NCH; t++) {
        *(bf16x8*)&Ks[grp][skey][sd0] = rk0;
        *(bf16x8*)&Ks[grp][skey][sd0 + 8] = rk1;
#pragma unroll
        for (int j = 0; j < 8; j++) {
            int row = sd0 + j;
            Vt[grp][row][skey ^ ((row >> 3) << 3)] = rv0[j];
            int row2 = sd0 + 8 + j;
            Vt[grp][row2][skey ^ ((row2 >> 3) << 3)] = rv1[j];
        }
        __syncthreads();

        if (t + 1 < NCH) {
            int kg = kgbase + (t + 1) * CK + skey;
            int lidx = kg >> 10, i = kg & 1023;
            size_t off = ((size_t)(lidx * 2048 + b * 1024 + i) << 11) + h * 64 + sd0;
            rk0 = *(const bf16x8*)(PKV + off);
            rk1 = *(const bf16x8*)(PKV + off + 8);
            rv0 = *(const bf16x8*)(PKV + off + 1024);
            rv1 = *(const bf16x8*)(PKV + off + 1032);
            int kloc = (kgbase + (t + 1) * CK) & 1023;
#pragma unroll
            for (int tile = 0; tile < 4; tile++)
                mkn[tile] = *(const unsigned int*)(mrow_p + kloc + tile * 16 + l4 * 4);
        }

        f32x4 s[4];
        __builtin_amdgcn_s_setprio(1);
#pragma unroll
        for (int tile = 0; tile < 4; tile++) {
            bf16x8 ka = *(const bf16x8*)&Ks[grp][tile * 16 + l16][l4 * 8];
            bf16x8 kb = *(const bf16x8*)&Ks[grp][tile * 16 + l16][32 + l4 * 8];
            f32x4 sz = fzero;
            sz = MFMA16(ka, qf[0], sz);
            sz = MFMA16(kb, qf[1], sz);
            s[tile] = sz;
        }
        __builtin_amdgcn_s_setprio(0);

        float pa = fmaxf(fmaxf(s[0][0], s[0][1]), fmaxf(s[0][2], s[0][3]));
        float pb = fmaxf(fmaxf(s[1][0], s[1][1]), fmaxf(s[1][2], s[1][3]));
        float pc = fmaxf(fmaxf(s[2][0], s[2][1]), fmaxf(s[2][2], s[2][3]));
        float pd = fmaxf(fmaxf(s[3][0], s[3][1]), fmaxf(s[3][2], s[3][3]));
        float pmax = fmaxf(fmaxf(pa, pb), fmaxf(pc, pd));
        pmax = fmaxf(pmax, __shfl_xor(pmax, 16));
        pmax = fmaxf(pmax, __shfl_xor(pmax, 32));
        if (__builtin_expect(pmax > m + 8.0f, 0)) {
            float sc = exp2_fast(m - pmax);
            lsum *= sc;
#pragma unroll
            for (int n = 0; n < 4; n++) accT[n] *= sc;
            m = pmax;
        }
        float psum = 0.0f;
#pragma unroll
        for (int tile = 0; tile < 4; tile++) {
            bf16x4 pk_;
#pragma unroll
            for (int r = 0; r < 4; r++) {
                float e = exp2_fast(s[tile][r] - m);
                e = ((mk[tile] >> (r * 8)) & 255u) ? 0.0f : e;
                psum += e;
                pk_[r] = (__bf16)e;
            }
            *(bf16x4*)&Ps[wave][l16][tile * 16 + l4 * 4] = pk_;
        }
        lsum += psum;
#pragma unroll
        for (int tile = 0; tile < 4; tile++) mk[tile] = mkn[tile];

        __builtin_amdgcn_s_setprio(1);
#pragma unroll
        for (int kk = 0; kk < 2; kk++) {
            bf16x8 pf = *(const bf16x8*)&Ps[wave][l16][kk * 32 + l4 * 8];
#pragma unroll
            for (int n = 0; n < 4; n++) {
                int row = n * 16 + l16;
                int colblk = (kk * 32 + l4 * 8) ^ ((row >> 3) << 3);
                bf16x8 vf = *(const bf16x8*)&Vt[grp][row][colblk];
                accT[n] = MFMA16(vf, pf, accT[n]);
            }
        }
        __builtin_amdgcn_s_setprio(0);
        __syncthreads();
    }

    lsum += __shfl_xor(lsum, 16);
    lsum += __shfl_xor(lsum, 32);

    float* exAcc = (float*)&Ks[0][0][0];
    float* exM = (float*)&Vt[0][0][0];
    float* exL = exM + 64;
    if (grp == 1) {
#pragma unroll
        for (int n = 0; n < 4; n++)
            *(f32x4*)&exAcc[(wv * 16 + l16) * 68 + n * 16 + l4 * 4] = accT[n];
        if (l4 == 0) { exM[wv * 16 + l16] = m; exL[wv * 16 + l16] = lsum; }
    }
    __syncthreads();
    if (grp == 0) {
        int qi = wv * 16 + l16;
        float m1 = exM[qi], l1 = exL[qi];
        float M = fmaxf(m, m1);
        float e0 = exp2_fast(m - M), e1 = exp2_fast(m1 - M);
        float inv = 1.0f / (lsum * e0 + l1 * e1);
        __bf16* crow = ctx + ((size_t)(b * 1024 + q0 + l16) << 10) + h * 64;
#pragma unroll
        for (int n = 0; n < 4; n++) {
            f32x4 a1 = *(const f32x4*)&exAcc[qi * 68 + n * 16 + l4 * 4];
            bf16x4 o;
#pragma unroll
            for (int r = 0; r < 4; r++) o[r] = (__bf16)((accT[n][r] * e0 + a1[r] * e1) * inv);
            *(bf16x4*)&crow[n * 16 + l4 * 4] = o;
        }
    }
}

// ---------------- launcher ----------------
extern "C" void kernel_launch(void* const* d_in, const int* in_sizes, int n_in,
                              void* d_out, int out_size, void* d_ws, size_t ws_size,
                              hipStream_t stream) {
    const float* x = (const float*)d_in[0];
    const float* memory_bank = (const float*)d_in[1];
    const unsigned char* attn_mask = (const unsigned char*)d_in[2];
    const float* ln1_g = (const float*)d_in[3];
    const float* ln1_b = (const float*)d_in[4];
    const float* Wq = (const float*)d_in[5];
    const float* Wk = (const float*)d_in[6];
    const float* Wv = (const float*)d_in[7];
    const float* Wo = (const float*)d_in[8];
    const float* ln2_g = (const float*)d_in[9];
    const float* ln2_b = (const float*)d_in[10];
    const float* W1 = (const float*)d_in[11];
    const float* b1 = (const float*)d_in[12];
    const float* W2 = (const float*)d_in[13];
    const float* b2 = (const float*)d_in[14];

    float* out = (float*)d_out;
    float* mem_out = out + 2097152;
    float* q_out = mem_out + 4 * 2097152;

    char* ws = (char*)d_ws;
    bool big = ws_size >= (70ull << 20);

    __bf16* PKV = (__bf16*)ws;  // [0,40) both modes
    __bf16 *Pq, *Wq_t, *Wkv_t, *ctx, *membf = nullptr, *qbf = nullptr;
    if (big) {
        membf = (__bf16*)(ws + (40ull << 20));   // [40,60) [10240][1024]
        qbf = membf + (size_t)8192 * 1024;
        Wq_t = (__bf16*)(ws + (60ull << 20));    // [60,62)
        Wkv_t = (__bf16*)(ws + (62ull << 20));   // [62,66)
        Pq = (__bf16*)(ws + (66ull << 20));      // [66,70)
        ctx = (__bf16*)(ws + (60ull << 20));     // [60,64) after proj GEMMs
    } else {
        Pq = (__bf16*)(ws + (40ull << 20));
        Wq_t = (__bf16*)(ws + (44ull << 20));
        Wkv_t = (__bf16*)(ws + (46ull << 20));
        ctx = (__bf16*)(ws + (44ull << 20));
    }
    // phase B (both modes; PKV/membf dead)
    __bf16* Wo_t = (__bf16*)ws;                   // [0,2)
    __bf16* W1_t = (__bf16*)(ws + (2ull << 20));  // [2,10)
    __bf16* W2_t = (__bf16*)(ws + (10ull << 20)); // [10,18)
    float* x2 = (float*)(ws + (18ull << 20));     // [18,26)
    __bf16* fln = (__bf16*)(ws + (26ull << 20));  // [26,30)
    __bf16* h1 = (__bf16*)(ws + (30ull << 20));   // [30,46)
    float* pc0 = (float*)(ws + (46ull << 20));    // [46,54) big only
    float* pc1 = (float*)(ws + (54ull << 20));    // [54,62) big only

    // 1. prep: copy bank (+bf16) and LN1 (+bf16 q)
    prep_kernel<<<4096, 256, 0, stream>>>(memory_bank, mem_out, membf, x, ln1_g, ln1_b,
                                          q_out, qbf);
    // 2. early transposes
    tr_early<<<3072, 256, 0, stream>>>(Wq, Wk, Wv, Wq_t, Wkv_t);

    // 3. fused projections (KV + Pq); Pq scale folds dh^-0.5 * log2(e)
    if (big)
        gemm_proj<true><<<1408, 256, 0, stream>>>(membf, Wkv_t, PKV, qbf, Wq_t, Pq);
    else
        gemm_proj<false><<<1408, 256, 0, stream>>>(mem_out, Wkv_t, PKV, q_out, Wq_t, Pq);

    // 4. attention
    attn_kernel<<<dim3(32, 16), 512, 0, stream>>>(Pq, PKV, attn_mask, ctx);

    // 5. late transposes (one launch)
    tr_late<<<9216, 256, 0, stream>>>(Wo, W1, W2, Wo_t, W1_t, W2_t);

    // 6. Wo + residual -> x2
    gemm_bt<1, true><<<128, 256, 0, stream>>>(ctx, Wo_t, x2, nullptr, x, 1024, 1024, 1.0f, 8);
    // 7. FFN
    ln_kernel<<<2048, 256, 0, stream>>>(x2, ln2_g, ln2_b, fln);
    gemm_bt<2, true><<<512, 256, 0, stream>>>(fln, W1_t, h1, b1, nullptr, 4096, 1024, 1.0f, 32);
    if (big) {
        gemm_w2<<<256, 256, 0, stream>>>(h1, W2_t, pc0, pc1);
        w2comb<<<2048, 256, 0, stream>>>(pc0, pc1, b2, x2, out);
    } else {
        gemm_bt<3, true><<<128, 256, 0, stream>>>(h1, W2_t, out, b2, x2, 1024, 4096, 1.0f, 8);
    }
}